// Round 6
// baseline (3965.259 us; speedup 1.0000x reference)
//
#include <hip/hip_runtime.h>
#include <stdint.h>

// ---------------------------------------------------------------------------
// Types / helpers
// ---------------------------------------------------------------------------
typedef short short8 __attribute__((ext_vector_type(8)));
typedef short short4v __attribute__((ext_vector_type(4)));
typedef float float4v __attribute__((ext_vector_type(4)));

__device__ __forceinline__ float b2f(short s) {
    return __uint_as_float(((unsigned)(unsigned short)s) << 16);
}
__device__ __forceinline__ short f2b(float f) {
    unsigned u = __float_as_uint(f);
    unsigned r = (u + 0x7fffu + ((u >> 16) & 1u)) >> 16;
    return (short)r;
}

// ---------------------------------------------------------------------------
// Fused fp32->bf16 converter: x (1048576 quads) + 8 weight buffers
// ---------------------------------------------------------------------------
__global__ void k_cvt_all(const float4v* __restrict__ xs,
                          const float4v* __restrict__ s0, const float4v* __restrict__ s1,
                          const float4v* __restrict__ s2, const float4v* __restrict__ s3,
                          const float4v* __restrict__ s4, const float4v* __restrict__ s5,
                          const float4v* __restrict__ s6, const float4v* __restrict__ s7,
                          short4v* __restrict__ xq, short4v* __restrict__ wq) {
    int i = blockIdx.x * blockDim.x + threadIdx.x;
    int stride = gridDim.x * blockDim.x;
    for (; i < 3538944; i += stride) {
        float4v v;
        short4v* dst;
        int di;
        if (i < 1048576) { v = xs[i]; dst = xq; di = i; }
        else {
            int j = i - 1048576;
            dst = wq; di = j;
            if      (j <   65536) v = s0[j];
            else if (j <  131072) v = s1[j -   65536];
            else if (j <  262144) v = s2[j -  131072];
            else if (j <  393216) v = s3[j -  262144];
            else if (j <  655360) v = s4[j -  393216];
            else if (j <  917504) v = s5[j -  655360];
            else if (j < 1441792) v = s6[j -  917504];
            else                  v = s7[j - 1441792];
        }
        short4v o;
        o[0] = f2b(v[0]); o[1] = f2b(v[1]); o[2] = f2b(v[2]); o[3] = f2b(v[3]);
        dst[di] = o;
    }
}

// ---------------------------------------------------------------------------
// Small prep: wc1 transpose+cvt, bias sum, zero lpad pad-rows / h bufs / flags
// ---------------------------------------------------------------------------
__global__ void k_small_prep(const float* __restrict__ wc1, short* __restrict__ wc1b,
                             const float* __restrict__ bih, const float* __restrict__ bhh,
                             float* __restrict__ bsum, short* __restrict__ lpad,
                             short* __restrict__ hs0, short* __restrict__ hs1,
                             int* __restrict__ arr) {
    int t0 = blockIdx.x * blockDim.x + threadIdx.x;
    int stride = gridDim.x * blockDim.x;
    for (int i = t0; i < 512 * 3072; i += stride) {
        int c = i / 3072, rr = i % 3072, dk = rr / 1024, h = rr % 1024;
        wc1b[i] = f2b(wc1[(c * 1024 + h) * 3 + dk]);
    }
    for (int i = t0; i < 4096; i += stride) bsum[i] = bih[i] + bhh[i];
    for (int i = t0; i < 16 * 1024; i += stride) {
        int b = i >> 11, r = (i >> 10) & 1, h = i & 1023;
        lpad[((long)(b * 1026 + r * 1025)) * 1024 + h] = 0;
    }
    for (int i = t0; i < 16384; i += stride) { hs0[i] = 0; hs1[i] = 0; }
    for (int i = t0; i < 128; i += stride) arr[i] = 0;
}

// ---------------------------------------------------------------------------
// Generic batched GEMM (BM=128):  C[m][n] = act( sum_k A[m][k]*B[n][k] + b[n] )
// Staging via global_load_lds width=16; XOR swizzle applied source-side.
// ---------------------------------------------------------------------------
__global__ __launch_bounds__(256) void k_gemm_bt(
    const short* __restrict__ A, const short* __restrict__ B,
    float* __restrict__ Cf, short* __restrict__ Cb,
    const float* __restrict__ bias,
    int M, int N, int K, int lda, int ldb, int ldc,
    int z0n, long sA0, long sA1, long sB0, long sB1, long sC0, long sC1,
    int act, int gap)
{
    __shared__ __align__(16) short lds[2 * 128 * 32];
    const int z = blockIdx.z;
    const int z0 = z % z0n, z1 = z / z0n;
    A += z1 * sA1 + z0 * sA0;
    B += z1 * sB1 + z0 * sB0;
    const long coff = z1 * sC1 + z0 * sC0;
    const int tn0 = blockIdx.x * 128, tm0 = blockIdx.y * 128;
    const int tid = threadIdx.x, ln = tid & 63, wv = tid >> 6;
    const int wr = wv >> 1, wc = wv & 1;

    const short* gbase[4];
    {
        const int gcol = (ln & 3) ^ ((ln >> 3) & 3);
#pragma unroll
        for (int j = 0; j < 4; ++j) {
            int c = wv * 4 + j;
            if (c < 8) {
                long grow = (long)(tm0 + c * 16 + (ln >> 2));
                if (gap) grow += 2 * (grow >> 10);
                gbase[j] = A + grow * (long)lda + gcol * 8;
            } else {
                gbase[j] = B + (long)(tn0 + (c - 8) * 16 + (ln >> 2)) * ldb + gcol * 8;
            }
        }
    }

    float4v acc[4][4];
#pragma unroll
    for (int i = 0; i < 4; ++i)
#pragma unroll
        for (int j = 0; j < 4; ++j) acc[i][j] = (float4v){0.f, 0.f, 0.f, 0.f};

    const int nk = K >> 5;
    for (int kt = 0; kt < nk; ++kt) {
        __syncthreads();
#pragma unroll
        for (int j = 0; j < 4; ++j) {
            int c = wv * 4 + j;
            __builtin_amdgcn_global_load_lds(
                (const __attribute__((address_space(1))) void*)(gbase[j] + kt * 32),
                (__attribute__((address_space(3))) void*)((short8*)lds + c * 64),
                16, 0, 0);
        }
        __syncthreads();

        short8 af[4], bf_[4];
        const int q = ln >> 4;
#pragma unroll
        for (int i = 0; i < 4; ++i) {
            int r = wr * 64 + i * 16 + (ln & 15);
            af[i] = ((short8*)lds)[r * 4 + (q ^ ((r >> 1) & 3))];
        }
#pragma unroll
        for (int j = 0; j < 4; ++j) {
            int r = wc * 64 + j * 16 + (ln & 15);
            bf_[j] = ((short8*)lds)[512 + r * 4 + (q ^ ((r >> 1) & 3))];
        }
#pragma unroll
        for (int i = 0; i < 4; ++i)
#pragma unroll
            for (int j = 0; j < 4; ++j)
                acc[i][j] = __builtin_amdgcn_mfma_f32_16x16x32_bf16(af[i], bf_[j], acc[i][j], 0, 0, 0);
    }

#pragma unroll
    for (int j = 0; j < 4; ++j) {
        int nglob = tn0 + wc * 64 + j * 16 + (ln & 15);
        float bv = bias ? bias[nglob] : 0.f;
#pragma unroll
        for (int i = 0; i < 4; ++i) {
#pragma unroll
            for (int r = 0; r < 4; ++r) {
                int mglob = tm0 + wr * 64 + i * 16 + (ln >> 4) * 4 + r;
                float v = acc[i][j][r] + bv;
                if (act == 1) v = (v >= 0.f) ? v : 0.25f * v;
                else if (act == 2) v = fmaxf(v, 0.f);
                long ci = coff + (long)mglob * ldc + nglob;
                if (Cf) Cf[ci] = v;
                if (Cb) Cb[ci] = f2b(v);
            }
        }
    }
}

// ---------------------------------------------------------------------------
// BM=64 variant (64x128 tile): doubles blocks/CU for N=512-class shapes where
// the 128-tile grid gives only 1 block/CU and the staging drain is exposed.
// Same slot/swizzle scheme: slots of 16 rows; A = slots 0..3, B = slots 4..11
// (B LDS base 256 short8). 3 staging calls/wave. acc[2][4], LDS 12 KB.
// ---------------------------------------------------------------------------
__global__ __launch_bounds__(256) void k_gemm_bt64(
    const short* __restrict__ A, const short* __restrict__ B,
    float* __restrict__ Cf, short* __restrict__ Cb,
    const float* __restrict__ bias,
    int M, int N, int K, int lda, int ldb, int ldc,
    int z0n, long sA0, long sA1, long sB0, long sB1, long sC0, long sC1,
    int act, int gap)
{
    __shared__ __align__(16) short lds[(64 + 128) * 32];
    const int z = blockIdx.z;
    const int z0 = z % z0n, z1 = z / z0n;
    A += z1 * sA1 + z0 * sA0;
    B += z1 * sB1 + z0 * sB0;
    const long coff = z1 * sC1 + z0 * sC0;
    const int tn0 = blockIdx.x * 128, tm0 = blockIdx.y * 64;
    const int tid = threadIdx.x, ln = tid & 63, wv = tid >> 6;
    const int wr = wv >> 1, wc = wv & 1;

    const short* gbase[3];
    {
        const int gcol = (ln & 3) ^ ((ln >> 3) & 3);
#pragma unroll
        for (int j = 0; j < 3; ++j) {
            int c = wv * 3 + j;
            if (c < 4) {
                long grow = (long)(tm0 + c * 16 + (ln >> 2));
                if (gap) grow += 2 * (grow >> 10);
                gbase[j] = A + grow * (long)lda + gcol * 8;
            } else {
                gbase[j] = B + (long)(tn0 + (c - 4) * 16 + (ln >> 2)) * ldb + gcol * 8;
            }
        }
    }

    float4v acc[2][4];
#pragma unroll
    for (int i = 0; i < 2; ++i)
#pragma unroll
        for (int j = 0; j < 4; ++j) acc[i][j] = (float4v){0.f, 0.f, 0.f, 0.f};

    const int nk = K >> 5;
    for (int kt = 0; kt < nk; ++kt) {
        __syncthreads();
#pragma unroll
        for (int j = 0; j < 3; ++j) {
            int c = wv * 3 + j;
            __builtin_amdgcn_global_load_lds(
                (const __attribute__((address_space(1))) void*)(gbase[j] + kt * 32),
                (__attribute__((address_space(3))) void*)((short8*)lds + c * 64),
                16, 0, 0);
        }
        __syncthreads();

        short8 af[2], bf_[4];
        const int q = ln >> 4;
#pragma unroll
        for (int i = 0; i < 2; ++i) {
            int r = wr * 32 + i * 16 + (ln & 15);
            af[i] = ((short8*)lds)[r * 4 + (q ^ ((r >> 1) & 3))];
        }
#pragma unroll
        for (int j = 0; j < 4; ++j) {
            int r = wc * 64 + j * 16 + (ln & 15);
            bf_[j] = ((short8*)lds)[256 + r * 4 + (q ^ ((r >> 1) & 3))];
        }
#pragma unroll
        for (int i = 0; i < 2; ++i)
#pragma unroll
            for (int j = 0; j < 4; ++j)
                acc[i][j] = __builtin_amdgcn_mfma_f32_16x16x32_bf16(af[i], bf_[j], acc[i][j], 0, 0, 0);
    }

#pragma unroll
    for (int j = 0; j < 4; ++j) {
        int nglob = tn0 + wc * 64 + j * 16 + (ln & 15);
        float bv = bias ? bias[nglob] : 0.f;
#pragma unroll
        for (int i = 0; i < 2; ++i) {
#pragma unroll
            for (int r = 0; r < 4; ++r) {
                int mglob = tm0 + wr * 32 + i * 16 + (ln >> 4) * 4 + r;
                float v = acc[i][j][r] + bv;
                if (act == 1) v = (v >= 0.f) ? v : 0.25f * v;
                else if (act == 2) v = fmaxf(v, 0.f);
                long ci = coff + (long)mglob * ldc + nglob;
                if (Cf) Cf[ci] = v;
                if (Cb) Cb[ci] = f2b(v);
            }
        }
    }
}

// ---------------------------------------------------------------------------
// Row softmax over 1024, bf16 in-place
// ---------------------------------------------------------------------------
__global__ __launch_bounds__(256) void k_softmax_rows_bf16(short* __restrict__ p) {
    long row = blockIdx.x;
    short* r = p + (row << 10);
    int tid = threadIdx.x;
    float v[4];
    float mx = -3.4e38f;
#pragma unroll
    for (int i = 0; i < 4; ++i) { v[i] = b2f(r[tid + (i << 8)]); mx = fmaxf(mx, v[i]); }
#pragma unroll
    for (int d = 32; d > 0; d >>= 1) mx = fmaxf(mx, __shfl_down(mx, d));
    __shared__ float red[4], red2[4];
    if ((tid & 63) == 0) red[tid >> 6] = mx;
    __syncthreads();
    mx = fmaxf(fmaxf(red[0], red[1]), fmaxf(red[2], red[3]));
    float s = 0.f;
#pragma unroll
    for (int i = 0; i < 4; ++i) { v[i] = __expf(v[i] - mx); s += v[i]; }
#pragma unroll
    for (int d = 32; d > 0; d >>= 1) s += __shfl_down(s, d);
    if ((tid & 63) == 0) red2[tid >> 6] = s;
    __syncthreads();
    s = red2[0] + red2[1] + red2[2] + red2[3];
    float inv = 1.f / s;
#pragma unroll
    for (int i = 0; i < 4; ++i) r[tid + (i << 8)] = f2b(v[i] * inv);
}

// ---------------------------------------------------------------------------
// LayerNorm over E=512 (bf16 in -> bf16 out), rows = 8192
// ---------------------------------------------------------------------------
__global__ __launch_bounds__(256) void k_layernorm(const short* __restrict__ y,
                                                   const float* __restrict__ gam,
                                                   const float* __restrict__ bet,
                                                   short* __restrict__ o) {
    const long row = blockIdx.x;
    const short* r = y + (row << 9);
    const int tid = threadIdx.x;
    float v0 = b2f(r[tid]), v1 = b2f(r[tid + 256]);
    float s = v0 + v1, ss = v0 * v0 + v1 * v1;
#pragma unroll
    for (int d = 32; d > 0; d >>= 1) { s += __shfl_down(s, d); ss += __shfl_down(ss, d); }
    __shared__ float rs_[4], rss[4];
    if ((tid & 63) == 0) { rs_[tid >> 6] = s; rss[tid >> 6] = ss; }
    __syncthreads();
    s = rs_[0] + rs_[1] + rs_[2] + rs_[3];
    ss = rss[0] + rss[1] + rss[2] + rss[3];
    float mean = s * (1.f / 512.f);
    float var = ss * (1.f / 512.f) - mean * mean;
    float rstd = rsqrtf(var + 1e-5f);
    short* out = o + (row << 9);
    out[tid]       = f2b((v0 - mean) * rstd * gam[tid]       + bet[tid]);
    out[tid + 256] = f2b((v1 - mean) * rstd * gam[tid + 256] + bet[tid + 256]);
}

// ---------------------------------------------------------------------------
// v [8192][2048] -> vT [32][512][1024] ([bn][d][s])
// ---------------------------------------------------------------------------
__global__ __launch_bounds__(256) void k_vT(const short* __restrict__ v, short* __restrict__ vT) {
    __shared__ short t[32][34];
    int bn = blockIdx.z, b = bn >> 2, n = bn & 3;
    int s0 = blockIdx.y * 32, d0 = blockIdx.x * 32;
    int lx = threadIdx.x & 31, ly = threadIdx.x >> 5;
#pragma unroll
    for (int i = 0; i < 4; ++i) {
        int s = ly + i * 8;
        t[s][lx] = v[(long)(b * 1024 + s0 + s) * 2048 + n * 512 + d0 + lx];
    }
    __syncthreads();
#pragma unroll
    for (int i = 0; i < 4; ++i) {
        int d = ly + i * 8;
        vT[((long)bn * 512 + d0 + d) * 1024 + s0 + lx] = t[lx][d];
    }
}

// ---------------------------------------------------------------------------
// Persistent LSTM — round-0 protocol VERBATIM (measured 3.24 ms, stable,
// no livelock outliers). Rounds 1-4 established this is the floor for the
// 64-block structure. DO NOT TOUCH.
// ---------------------------------------------------------------------------
__global__ __launch_bounds__(256) void k_lstm(
    const short* __restrict__ whh, const short* __restrict__ igb,
    short* __restrict__ hA, short* __restrict__ hB,
    short* __restrict__ lstm_pad, int* __restrict__ arr)
{
    const int g = blockIdx.x;            // 0..63, owns units g*16..g*16+15
    const int tid = threadIdx.x;
    const int ln = tid & 63, wv = tid >> 6;
    const int kbase = wv * 256 + ((ln >> 4) << 3);
    const int arow = ln & 15;            // batch rows; 8..15 stay zero

    short8 wf[4][8];
#pragma unroll
    for (int q = 0; q < 4; ++q) {
        long row = (long)q * 1024 + g * 16 + (ln & 15);
#pragma unroll
        for (int kk = 0; kk < 8; ++kk)
            wf[q][kk] = *(const short8*)&whh[row * 1024 + kbase + kk * 32];
    }

    __shared__ float part[4][16][68];
    const int gm = tid >> 4, gu = tid & 15;   // gate threads tid<128: batch, unit
    float c_prev = 0.f;
    float igv[4];
    if (tid < 128) {
#pragma unroll
        for (int q = 0; q < 4; ++q)
            igv[q] = b2f(igb[((long)gm * 1024 + 0) * 4096 + q * 1024 + g * 16 + gu]);
    }

    for (int step = 0; step < 1024; ++step) {
        const short* hp = (step & 1) ? hB : hA;
        short8 af[8];
        if (arow < 8) {
            const unsigned long long* hq =
                (const unsigned long long*)(hp + arow * 1024 + kbase);
#pragma unroll
            for (int kk = 0; kk < 8; ++kk) {
                union { unsigned long long u[2]; short8 s; } cv;
                cv.u[0] = __hip_atomic_load(hq + kk * 8,     __ATOMIC_RELAXED, __HIP_MEMORY_SCOPE_AGENT);
                cv.u[1] = __hip_atomic_load(hq + kk * 8 + 1, __ATOMIC_RELAXED, __HIP_MEMORY_SCOPE_AGENT);
                af[kk] = cv.s;
            }
        } else {
#pragma unroll
            for (int kk = 0; kk < 8; ++kk) af[kk] = (short8){0, 0, 0, 0, 0, 0, 0, 0};
        }

        float4v acc[4];
#pragma unroll
        for (int q = 0; q < 4; ++q) acc[q] = (float4v){0.f, 0.f, 0.f, 0.f};
#pragma unroll
        for (int kk = 0; kk < 8; ++kk)
#pragma unroll
            for (int q = 0; q < 4; ++q)
                acc[q] = __builtin_amdgcn_mfma_f32_16x16x32_bf16(af[kk], wf[q][kk], acc[q], 0, 0, 0);

#pragma unroll
        for (int q = 0; q < 4; ++q)
#pragma unroll
            for (int rr = 0; rr < 4; ++rr)
                part[wv][(ln >> 4) * 4 + rr][q * 16 + (ln & 15)] = acc[q][rr];
        __syncthreads();

        if (tid < 128) {
            float psum[4];
#pragma unroll
            for (int q = 0; q < 4; ++q)
                psum[q] = part[0][gm][q * 16 + gu] + part[1][gm][q * 16 + gu]
                        + part[2][gm][q * 16 + gu] + part[3][gm][q * 16 + gu];
            float g0 = psum[0] + igv[0];
            float g1 = psum[1] + igv[1];
            float g2 = psum[2] + igv[2];
            float g3 = psum[3] + igv[3];
            float iv = 1.f / (1.f + __expf(-g0));
            float fv = 1.f / (1.f + __expf(-g1));
            float gv = 2.f / (1.f + __expf(-2.f * g2)) - 1.f;
            float ov = 1.f / (1.f + __expf(-g3));
            float c = fv * c_prev + iv * gv;
            c_prev = c;
            float h = ov * (2.f / (1.f + __expf(-2.f * c)) - 1.f);
            short hb16 = f2b(h);
            short* hn = (step & 1) ? hA : hB;
            __hip_atomic_store(&hn[gm * 1024 + g * 16 + gu], hb16,
                               __ATOMIC_RELAXED, __HIP_MEMORY_SCOPE_AGENT);
            lstm_pad[((long)gm * 1026 + step + 1) * 1024 + g * 16 + gu] = hb16;
        }

        __syncthreads();   // drain: h stores acked before flag
        if (tid == 0)
            __hip_atomic_store(&arr[g], step + 1, __ATOMIC_RELAXED, __HIP_MEMORY_SCOPE_AGENT);
        if (tid < 128 && step + 1 < 1024) {
#pragma unroll
            for (int q = 0; q < 4; ++q)
                igv[q] = b2f(igb[((long)gm * 1024 + step + 1) * 4096 + q * 1024 + g * 16 + gu]);
        }
        if (wv == 0) {
            const int target = step + 1;
            long att = 0;
            while (true) {
                int f0 = __hip_atomic_load(&arr[ln], __ATOMIC_RELAXED, __HIP_MEMORY_SCOPE_AGENT);
                if (__all(f0 >= target)) break;
                if (++att > 20000000L) break;   // never hang
                __builtin_amdgcn_s_sleep(1);
            }
        }
        __syncthreads();
    }
}

// ---------------------------------------------------------------------------
// conv2: a1 [8192][512] bf16 (relu'd), w [2][512][3] staged in LDS.
// ---------------------------------------------------------------------------
__global__ __launch_bounds__(256) void k_conv2(const short* __restrict__ a1,
                                               const float* __restrict__ w,
                                               const float* __restrict__ bias,
                                               float* __restrict__ a2) {
    __shared__ float wl[1536];
    int blk = blockIdx.x;
    int b = blk >> 3, c = (blk >> 2) & 1, t0 = (blk & 3) * 256;
    int tid = threadIdx.x;
    for (int i = tid; i < 1536; i += 256) wl[i] = w[c * 1536 + i];
    __syncthreads();
    int t = t0 + tid;
    float s = bias[c];
    for (int dk = 0; dk < 3; ++dk) {
        int tt = t + dk - 1;
        if (tt < 0 || tt >= 1024) continue;
        const short8* arow = (const short8*)(a1 + (long)(b * 1024 + tt) * 512);
#pragma unroll 4
        for (int j = 0; j < 64; ++j) {
            short8 v = arow[j];
#pragma unroll
            for (int u = 0; u < 8; ++u)
                s += b2f(v[u]) * wl[(j * 8 + u) * 3 + dk];
        }
    }
    a2[(b * 2 + c) * 1024 + t] = s;
}

// ---------------------------------------------------------------------------
// feat[b][c][h] = sum_t softmax(a2[bc])[t] * lstm_pad[b][t+1][h]
// ---------------------------------------------------------------------------
__global__ __launch_bounds__(256) void k_feat(const float* __restrict__ a2,
                                              const short* __restrict__ lstm_pad,
                                              float* __restrict__ out) {
    int blk = blockIdx.x;
    int bc = blk >> 2, qh = blk & 3;
    int b = bc >> 1;
    int tid = threadIdx.x;
    int h = qh * 256 + tid;
    __shared__ float aw[1024];
    __shared__ float red[4], red2[4];
    float v[4];
    float mx = -3.4e38f;
#pragma unroll
    for (int i = 0; i < 4; ++i) { v[i] = a2[bc * 1024 + tid + (i << 8)]; mx = fmaxf(mx, v[i]); }
#pragma unroll
    for (int d = 32; d > 0; d >>= 1) mx = fmaxf(mx, __shfl_down(mx, d));
    if ((tid & 63) == 0) red[tid >> 6] = mx;
    __syncthreads();
    mx = fmaxf(fmaxf(red[0], red[1]), fmaxf(red[2], red[3]));
    float s = 0.f;
#pragma unroll
    for (int i = 0; i < 4; ++i) { v[i] = __expf(v[i] - mx); s += v[i]; }
#pragma unroll
    for (int d = 32; d > 0; d >>= 1) s += __shfl_down(s, d);
    if ((tid & 63) == 0) red2[tid >> 6] = s;
    __syncthreads();
    s = red2[0] + red2[1] + red2[2] + red2[3];
    float inv = 1.f / s;
#pragma unroll
    for (int i = 0; i < 4; ++i) aw[tid + (i << 8)] = v[i] * inv;
    __syncthreads();
    float acc = 0.f;
#pragma unroll 16
    for (int t = 0; t < 1024; ++t)
        acc += aw[t] * b2f(lstm_pad[((long)(b * 1026 + t + 1)) * 1024 + h]);
    out[bc * 1024 + h] = acc;
}

// ---------------------------------------------------------------------------
// Host orchestration
// ---------------------------------------------------------------------------
static void gemm_bt(hipStream_t st, const short* A, const short* B, float* Cf, short* Cb,
                    const float* bias, int M, int N, int K, int lda, int ldb, int ldc,
                    int z, int z0n, long sA0, long sA1, long sB0, long sB1, long sC0, long sC1,
                    int act, int gap) {
    dim3 grid(N / 128, M / 128, z);
    k_gemm_bt<<<grid, dim3(256), 0, st>>>(A, B, Cf, Cb, bias, M, N, K, lda, ldb, ldc,
                                          z0n, sA0, sA1, sB0, sB1, sC0, sC1, act, gap);
}

static void gemm_bt64(hipStream_t st, const short* A, const short* B, float* Cf, short* Cb,
                      const float* bias, int M, int N, int K, int lda, int ldb, int ldc,
                      int z, int z0n, long sA0, long sA1, long sB0, long sB1, long sC0, long sC1,
                      int act, int gap) {
    dim3 grid(N / 128, M / 64, z);
    k_gemm_bt64<<<grid, dim3(256), 0, st>>>(A, B, Cf, Cb, bias, M, N, K, lda, ldb, ldc,
                                            z0n, sA0, sA1, sB0, sB1, sC0, sC1, act, gap);
}

extern "C" void kernel_launch(void* const* d_in, const int* in_sizes, int n_in,
                              void* d_out, int out_size, void* d_ws, size_t ws_size,
                              hipStream_t stream) {
    if (ws_size < 199409920u) return;

    const float* x     = (const float*)d_in[0];
    const float* w_in1 = (const float*)d_in[1];
    const float* b_in1 = (const float*)d_in[2];
    const float* w_in2 = (const float*)d_in[3];
    const float* b_in2 = (const float*)d_in[4];
    const float* w_q   = (const float*)d_in[5];
    const float* b_q   = (const float*)d_in[6];
    const float* w_k   = (const float*)d_in[7];
    const float* b_k   = (const float*)d_in[8];
    const float* w_v   = (const float*)d_in[9];
    const float* b_v   = (const float*)d_in[10];
    const float* w_p   = (const float*)d_in[11];
    const float* b_p   = (const float*)d_in[12];
    const float* ln_g  = (const float*)d_in[13];
    const float* ln_b  = (const float*)d_in[14];
    const float* w_ih  = (const float*)d_in[15];
    const float* w_hh  = (const float*)d_in[16];
    const float* b_ih  = (const float*)d_in[17];
    const float* b_hh  = (const float*)d_in[18];
    const float* w_c1  = (const float*)d_in[19];
    const float* b_c1  = (const float*)d_in[20];
    const float* w_c2  = (const float*)d_in[21];
    const float* b_c2  = (const float*)d_in[22];

    char* ws = (char*)d_ws;
    // ---- static region ----
    short* w1b  = (short*)(ws + 0);
    short* w2b  = (short*)(ws + 524288);
    short* wqb  = (short*)(ws + 1048576);
    short* wkb  = (short*)(ws + 2097152);
    short* wvb  = (short*)(ws + 3145728);
    short* wpb  = (short*)(ws + 5242880);
    short* wihb = (short*)(ws + 7340032);
    short* whhb = (short*)(ws + 11534336);
    short* wc1b = (short*)(ws + 19922944);
    float* bsum = (float*)(ws + 23068672);
    short* hs0  = (short*)(ws + 23085056);     // 32 KB
    short* hs1  = (short*)(ws + 23117824);     // 32 KB
    int*   arr  = (int*)  (ws + 23150592);     // 512 B
    float* a2   = (float*)(ws + 23150848);
    short* lpad = (short*)(ws + 23216384);
    // ---- dynamic region D0 = 40,026,368 ----
    const size_t D0 = 40026368u;
    short* xbf   = (short*)(ws + D0);
    short* h1bf  = (short*)(ws + D0 + 8388608);
    short* h2bf  = (short*)(ws + D0 + 16777216);
    short* qbf   = (short*)(ws + D0 + 25165824);
    short* kbf   = (short*)(ws + D0 + 41943040);
    short* vbf   = (short*)(ws + D0 + 58720256);
    short* vTbf  = (short*)(ws + D0 + 92274688);
    short* scb   = (short*)(ws + D0 + 58720256);   // 32 MB (vbf slot, dead after vT)
    short* obf   = (short*)(ws + D0 + 125829120);
    short* ybf   = (short*)(ws + D0 + 58720256);   // scb dead by then
    short* ylnbf = (short*)(ws + D0 + 67108864);
    short* igb   = (short*)(ws + D0 + 92274688);
    short* a1bf  = (short*)(ws + D0);

    k_cvt_all<<<dim3(4096), dim3(256), 0, stream>>>(
        (const float4v*)x,
        (const float4v*)w_in1, (const float4v*)w_in2, (const float4v*)w_q, (const float4v*)w_k,
        (const float4v*)w_v, (const float4v*)w_p, (const float4v*)w_ih, (const float4v*)w_hh,
        (short4v*)xbf, (short4v*)w1b);
    k_small_prep<<<dim3(128), dim3(256), 0, stream>>>(
        w_c1, wc1b, b_ih, b_hh, bsum, lpad, hs0, hs1, arr);

    gemm_bt64(stream, xbf, w1b, nullptr, h1bf, b_in1, 8192, 512, 512, 512, 512, 512,
              1, 1, 0, 0, 0, 0, 0, 0, 1, 0);
    gemm_bt64(stream, h1bf, w2b, nullptr, h2bf, b_in2, 8192, 512, 512, 512, 512, 512,
              1, 1, 0, 0, 0, 0, 0, 0, 0, 0);
    gemm_bt64(stream, h2bf, wqb, nullptr, qbf, b_q, 8192, 1024, 512, 512, 512, 1024,
              1, 1, 0, 0, 0, 0, 0, 0, 0, 0);
    gemm_bt64(stream, h2bf, wkb, nullptr, kbf, b_k, 8192, 1024, 512, 512, 512, 1024,
              1, 1, 0, 0, 0, 0, 0, 0, 0, 0);
    gemm_bt(stream, h2bf, wvb, nullptr, vbf, b_v, 8192, 2048, 512, 512, 512, 2048,
            1, 1, 0, 0, 0, 0, 0, 0, 0, 0);
    k_vT<<<dim3(16, 32, 32), dim3(256), 0, stream>>>(vbf, vTbf);

    // attention: 4 batches per iteration (z = 4 batches x 4 heads = 16)
    for (int bg = 0; bg < 2; ++bg) {
        const short* qb = qbf + (long)bg * 4194304;
        const short* kb = kbf + (long)bg * 4194304;
        gemm_bt(stream, qb, kb, nullptr, scb, nullptr, 1024, 1024, 256, 1024, 1024, 1024,
                16, 4, 256, 1048576, 256, 1048576, 1048576, 4194304, 0, 0);
        k_softmax_rows_bf16<<<dim3(16384), dim3(256), 0, stream>>>(scb);
        gemm_bt64(stream, scb, vTbf + (long)bg * 8388608, nullptr, obf + (long)bg * 8388608, nullptr,
                  1024, 512, 1024, 1024, 1024, 2048,
                  16, 4, 1048576, 4194304, 524288, 2097152, 512, 2097152, 0, 0);
    }

    gemm_bt64(stream, obf, wpb, nullptr, ybf, b_p, 8192, 512, 2048, 2048, 2048, 512,
              1, 1, 0, 0, 0, 0, 0, 0, 0, 0);
    k_layernorm<<<dim3(8192), dim3(256), 0, stream>>>(ybf, ln_g, ln_b, ylnbf);
    gemm_bt(stream, ylnbf, wihb, nullptr, igb, bsum, 8192, 4096, 512, 512, 512, 4096,
            1, 1, 0, 0, 0, 0, 0, 0, 0, 0);
    k_lstm<<<dim3(64), dim3(256), 0, stream>>>(whhb, igb, hs0, hs1, lpad, arr);
    gemm_bt64(stream, lpad, wc1b, nullptr, a1bf, b_c1, 8192, 512, 3072, 1024, 3072, 512,
              1, 1, 0, 0, 0, 0, 0, 0, 2, 1);
    k_conv2<<<dim3(64), dim3(256), 0, stream>>>(a1bf, w_c2, b_c2, a2);
    k_feat<<<dim3(64), dim3(256), 0, stream>>>(a2, lpad, (float*)d_out);
    (void)in_sizes; (void)n_in; (void)out_size; (void)ws_size;
}

// Round 7
// 3905.287 us; speedup vs baseline: 1.0154x; 1.0154x over previous
//
#include <hip/hip_runtime.h>
#include <stdint.h>

// ---------------------------------------------------------------------------
// Types / helpers
// ---------------------------------------------------------------------------
typedef short short8 __attribute__((ext_vector_type(8)));
typedef short short4v __attribute__((ext_vector_type(4)));
typedef float float4v __attribute__((ext_vector_type(4)));

__device__ __forceinline__ float b2f(short s) {
    return __uint_as_float(((unsigned)(unsigned short)s) << 16);
}
__device__ __forceinline__ short f2b(float f) {
    unsigned u = __float_as_uint(f);
    unsigned r = (u + 0x7fffu + ((u >> 16) & 1u)) >> 16;
    return (short)r;
}

// ---------------------------------------------------------------------------
// Fused fp32->bf16 converter: x (1048576 quads) + 8 weight buffers
// ---------------------------------------------------------------------------
__global__ void k_cvt_all(const float4v* __restrict__ xs,
                          const float4v* __restrict__ s0, const float4v* __restrict__ s1,
                          const float4v* __restrict__ s2, const float4v* __restrict__ s3,
                          const float4v* __restrict__ s4, const float4v* __restrict__ s5,
                          const float4v* __restrict__ s6, const float4v* __restrict__ s7,
                          short4v* __restrict__ xq, short4v* __restrict__ wq) {
    int i = blockIdx.x * blockDim.x + threadIdx.x;
    int stride = gridDim.x * blockDim.x;
    for (; i < 3538944; i += stride) {
        float4v v;
        short4v* dst;
        int di;
        if (i < 1048576) { v = xs[i]; dst = xq; di = i; }
        else {
            int j = i - 1048576;
            dst = wq; di = j;
            if      (j <   65536) v = s0[j];
            else if (j <  131072) v = s1[j -   65536];
            else if (j <  262144) v = s2[j -  131072];
            else if (j <  393216) v = s3[j -  262144];
            else if (j <  655360) v = s4[j -  393216];
            else if (j <  917504) v = s5[j -  655360];
            else if (j < 1441792) v = s6[j -  917504];
            else                  v = s7[j - 1441792];
        }
        short4v o;
        o[0] = f2b(v[0]); o[1] = f2b(v[1]); o[2] = f2b(v[2]); o[3] = f2b(v[3]);
        dst[di] = o;
    }
}

// ---------------------------------------------------------------------------
// Small prep: wc1 transpose+cvt, bias sum, zero lpad pad-rows / h bufs /
// flags (64 ints only — avoid a2 overlap), a2 init = conv2 bias.
// ---------------------------------------------------------------------------
__global__ void k_small_prep(const float* __restrict__ wc1, short* __restrict__ wc1b,
                             const float* __restrict__ bih, const float* __restrict__ bhh,
                             float* __restrict__ bsum, short* __restrict__ lpad,
                             short* __restrict__ hs0, short* __restrict__ hs1,
                             int* __restrict__ arr, const float* __restrict__ bc2,
                             float* __restrict__ a2) {
    int t0 = blockIdx.x * blockDim.x + threadIdx.x;
    int stride = gridDim.x * blockDim.x;
    for (int i = t0; i < 512 * 3072; i += stride) {
        int c = i / 3072, rr = i % 3072, dk = rr / 1024, h = rr % 1024;
        wc1b[i] = f2b(wc1[(c * 1024 + h) * 3 + dk]);
    }
    for (int i = t0; i < 4096; i += stride) bsum[i] = bih[i] + bhh[i];
    for (int i = t0; i < 16 * 1024; i += stride) {
        int b = i >> 11, r = (i >> 10) & 1, h = i & 1023;
        lpad[((long)(b * 1026 + r * 1025)) * 1024 + h] = 0;
    }
    for (int i = t0; i < 16384; i += stride) { hs0[i] = 0; hs1[i] = 0; }
    for (int i = t0; i < 64; i += stride) arr[i] = 0;
    for (int i = t0; i < 16384; i += stride) a2[i] = bc2[(i >> 10) & 1];
}

// ---------------------------------------------------------------------------
// Generic batched GEMM (BM=128).  bias2/nsplit: two-segment bias for fused
// N-dims (nglob < nsplit -> bias, else bias2[nglob-nsplit]).
// ---------------------------------------------------------------------------
__global__ __launch_bounds__(256) void k_gemm_bt(
    const short* __restrict__ A, const short* __restrict__ B,
    float* __restrict__ Cf, short* __restrict__ Cb,
    const float* __restrict__ bias,
    int M, int N, int K, int lda, int ldb, int ldc,
    int z0n, long sA0, long sA1, long sB0, long sB1, long sC0, long sC1,
    int act, int gap, const float* __restrict__ bias2, int nsplit)
{
    __shared__ __align__(16) short lds[2 * 128 * 32];
    const int z = blockIdx.z;
    const int z0 = z % z0n, z1 = z / z0n;
    A += z1 * sA1 + z0 * sA0;
    B += z1 * sB1 + z0 * sB0;
    const long coff = z1 * sC1 + z0 * sC0;
    const int tn0 = blockIdx.x * 128, tm0 = blockIdx.y * 128;
    const int tid = threadIdx.x, ln = tid & 63, wv = tid >> 6;
    const int wr = wv >> 1, wc = wv & 1;

    const short* gbase[4];
    {
        const int gcol = (ln & 3) ^ ((ln >> 3) & 3);
#pragma unroll
        for (int j = 0; j < 4; ++j) {
            int c = wv * 4 + j;
            if (c < 8) {
                long grow = (long)(tm0 + c * 16 + (ln >> 2));
                if (gap) grow += 2 * (grow >> 10);
                gbase[j] = A + grow * (long)lda + gcol * 8;
            } else {
                gbase[j] = B + (long)(tn0 + (c - 8) * 16 + (ln >> 2)) * ldb + gcol * 8;
            }
        }
    }

    float4v acc[4][4];
#pragma unroll
    for (int i = 0; i < 4; ++i)
#pragma unroll
        for (int j = 0; j < 4; ++j) acc[i][j] = (float4v){0.f, 0.f, 0.f, 0.f};

    const int nk = K >> 5;
    for (int kt = 0; kt < nk; ++kt) {
        __syncthreads();
#pragma unroll
        for (int j = 0; j < 4; ++j) {
            int c = wv * 4 + j;
            __builtin_amdgcn_global_load_lds(
                (const __attribute__((address_space(1))) void*)(gbase[j] + kt * 32),
                (__attribute__((address_space(3))) void*)((short8*)lds + c * 64),
                16, 0, 0);
        }
        __syncthreads();

        short8 af[4], bf_[4];
        const int q = ln >> 4;
#pragma unroll
        for (int i = 0; i < 4; ++i) {
            int r = wr * 64 + i * 16 + (ln & 15);
            af[i] = ((short8*)lds)[r * 4 + (q ^ ((r >> 1) & 3))];
        }
#pragma unroll
        for (int j = 0; j < 4; ++j) {
            int r = wc * 64 + j * 16 + (ln & 15);
            bf_[j] = ((short8*)lds)[512 + r * 4 + (q ^ ((r >> 1) & 3))];
        }
#pragma unroll
        for (int i = 0; i < 4; ++i)
#pragma unroll
            for (int j = 0; j < 4; ++j)
                acc[i][j] = __builtin_amdgcn_mfma_f32_16x16x32_bf16(af[i], bf_[j], acc[i][j], 0, 0, 0);
    }

#pragma unroll
    for (int j = 0; j < 4; ++j) {
        int nglob = tn0 + wc * 64 + j * 16 + (ln & 15);
        float bv = 0.f;
        if (bias) bv = (bias2 && nglob >= nsplit) ? bias2[nglob - nsplit] : bias[nglob];
#pragma unroll
        for (int i = 0; i < 4; ++i) {
#pragma unroll
            for (int r = 0; r < 4; ++r) {
                int mglob = tm0 + wr * 64 + i * 16 + (ln >> 4) * 4 + r;
                float v = acc[i][j][r] + bv;
                if (act == 1) v = (v >= 0.f) ? v : 0.25f * v;
                else if (act == 2) v = fmaxf(v, 0.f);
                long ci = coff + (long)mglob * ldc + nglob;
                if (Cf) Cf[ci] = v;
                if (Cb) Cb[ci] = f2b(v);
            }
        }
    }
}

// ---------------------------------------------------------------------------
// BM=64 variant (64x128 tile).
// ---------------------------------------------------------------------------
__global__ __launch_bounds__(256) void k_gemm_bt64(
    const short* __restrict__ A, const short* __restrict__ B,
    float* __restrict__ Cf, short* __restrict__ Cb,
    const float* __restrict__ bias,
    int M, int N, int K, int lda, int ldb, int ldc,
    int z0n, long sA0, long sA1, long sB0, long sB1, long sC0, long sC1,
    int act, int gap, const float* __restrict__ bias2, int nsplit)
{
    __shared__ __align__(16) short lds[(64 + 128) * 32];
    const int z = blockIdx.z;
    const int z0 = z % z0n, z1 = z / z0n;
    A += z1 * sA1 + z0 * sA0;
    B += z1 * sB1 + z0 * sB0;
    const long coff = z1 * sC1 + z0 * sC0;
    const int tn0 = blockIdx.x * 128, tm0 = blockIdx.y * 64;
    const int tid = threadIdx.x, ln = tid & 63, wv = tid >> 6;
    const int wr = wv >> 1, wc = wv & 1;

    const short* gbase[3];
    {
        const int gcol = (ln & 3) ^ ((ln >> 3) & 3);
#pragma unroll
        for (int j = 0; j < 3; ++j) {
            int c = wv * 3 + j;
            if (c < 4) {
                long grow = (long)(tm0 + c * 16 + (ln >> 2));
                if (gap) grow += 2 * (grow >> 10);
                gbase[j] = A + grow * (long)lda + gcol * 8;
            } else {
                gbase[j] = B + (long)(tn0 + (c - 4) * 16 + (ln >> 2)) * ldb + gcol * 8;
            }
        }
    }

    float4v acc[2][4];
#pragma unroll
    for (int i = 0; i < 2; ++i)
#pragma unroll
        for (int j = 0; j < 4; ++j) acc[i][j] = (float4v){0.f, 0.f, 0.f, 0.f};

    const int nk = K >> 5;
    for (int kt = 0; kt < nk; ++kt) {
        __syncthreads();
#pragma unroll
        for (int j = 0; j < 3; ++j) {
            int c = wv * 3 + j;
            __builtin_amdgcn_global_load_lds(
                (const __attribute__((address_space(1))) void*)(gbase[j] + kt * 32),
                (__attribute__((address_space(3))) void*)((short8*)lds + c * 64),
                16, 0, 0);
        }
        __syncthreads();

        short8 af[2], bf_[4];
        const int q = ln >> 4;
#pragma unroll
        for (int i = 0; i < 2; ++i) {
            int r = wr * 32 + i * 16 + (ln & 15);
            af[i] = ((short8*)lds)[r * 4 + (q ^ ((r >> 1) & 3))];
        }
#pragma unroll
        for (int j = 0; j < 4; ++j) {
            int r = wc * 64 + j * 16 + (ln & 15);
            bf_[j] = ((short8*)lds)[256 + r * 4 + (q ^ ((r >> 1) & 3))];
        }
#pragma unroll
        for (int i = 0; i < 2; ++i)
#pragma unroll
            for (int j = 0; j < 4; ++j)
                acc[i][j] = __builtin_amdgcn_mfma_f32_16x16x32_bf16(af[i], bf_[j], acc[i][j], 0, 0, 0);
    }

#pragma unroll
    for (int j = 0; j < 4; ++j) {
        int nglob = tn0 + wc * 64 + j * 16 + (ln & 15);
        float bv = 0.f;
        if (bias) bv = (bias2 && nglob >= nsplit) ? bias2[nglob - nsplit] : bias[nglob];
#pragma unroll
        for (int i = 0; i < 2; ++i) {
#pragma unroll
            for (int r = 0; r < 4; ++r) {
                int mglob = tm0 + wr * 32 + i * 16 + (ln >> 4) * 4 + r;
                float v = acc[i][j][r] + bv;
                if (act == 1) v = (v >= 0.f) ? v : 0.25f * v;
                else if (act == 2) v = fmaxf(v, 0.f);
                long ci = coff + (long)mglob * ldc + nglob;
                if (Cf) Cf[ci] = v;
                if (Cb) Cb[ci] = f2b(v);
            }
        }
    }
}

// ---------------------------------------------------------------------------
// conv1 combine: a1 = bf16(relu(p0 + p1 + b_c1[n]))
// ---------------------------------------------------------------------------
__global__ __launch_bounds__(256) void k_comb1(const float4v* __restrict__ p0,
                                               const float4v* __restrict__ p1,
                                               const float* __restrict__ bias,
                                               short4v* __restrict__ o) {
    int i = blockIdx.x * blockDim.x + threadIdx.x;
    int stride = gridDim.x * blockDim.x;
    for (; i < 1048576; i += stride) {
        float4v a = p0[i], b = p1[i];
        short4v r;
#pragma unroll
        for (int u = 0; u < 4; ++u) {
            float v = a[u] + b[u] + bias[(i * 4 + u) & 511];
            r[u] = f2b(fmaxf(v, 0.f));
        }
        o[i] = r;
    }
}

// ---------------------------------------------------------------------------
// Row softmax over 1024, bf16 in-place
// ---------------------------------------------------------------------------
__global__ __launch_bounds__(256) void k_softmax_rows_bf16(short* __restrict__ p) {
    long row = blockIdx.x;
    short* r = p + (row << 10);
    int tid = threadIdx.x;
    float v[4];
    float mx = -3.4e38f;
#pragma unroll
    for (int i = 0; i < 4; ++i) { v[i] = b2f(r[tid + (i << 8)]); mx = fmaxf(mx, v[i]); }
#pragma unroll
    for (int d = 32; d > 0; d >>= 1) mx = fmaxf(mx, __shfl_down(mx, d));
    __shared__ float red[4], red2[4];
    if ((tid & 63) == 0) red[tid >> 6] = mx;
    __syncthreads();
    mx = fmaxf(fmaxf(red[0], red[1]), fmaxf(red[2], red[3]));
    float s = 0.f;
#pragma unroll
    for (int i = 0; i < 4; ++i) { v[i] = __expf(v[i] - mx); s += v[i]; }
#pragma unroll
    for (int d = 32; d > 0; d >>= 1) s += __shfl_down(s, d);
    if ((tid & 63) == 0) red2[tid >> 6] = s;
    __syncthreads();
    s = red2[0] + red2[1] + red2[2] + red2[3];
    float inv = 1.f / s;
#pragma unroll
    for (int i = 0; i < 4; ++i) r[tid + (i << 8)] = f2b(v[i] * inv);
}

// ---------------------------------------------------------------------------
// LayerNorm over E=512 (bf16 in -> bf16 out), rows = 8192
// ---------------------------------------------------------------------------
__global__ __launch_bounds__(256) void k_layernorm(const short* __restrict__ y,
                                                   const float* __restrict__ gam,
                                                   const float* __restrict__ bet,
                                                   short* __restrict__ o) {
    const long row = blockIdx.x;
    const short* r = y + (row << 9);
    const int tid = threadIdx.x;
    float v0 = b2f(r[tid]), v1 = b2f(r[tid + 256]);
    float s = v0 + v1, ss = v0 * v0 + v1 * v1;
#pragma unroll
    for (int d = 32; d > 0; d >>= 1) { s += __shfl_down(s, d); ss += __shfl_down(ss, d); }
    __shared__ float rs_[4], rss[4];
    if ((tid & 63) == 0) { rs_[tid >> 6] = s; rss[tid >> 6] = ss; }
    __syncthreads();
    s = rs_[0] + rs_[1] + rs_[2] + rs_[3];
    ss = rss[0] + rss[1] + rss[2] + rss[3];
    float mean = s * (1.f / 512.f);
    float var = ss * (1.f / 512.f) - mean * mean;
    float rstd = rsqrtf(var + 1e-5f);
    short* out = o + (row << 9);
    out[tid]       = f2b((v0 - mean) * rstd * gam[tid]       + bet[tid]);
    out[tid + 256] = f2b((v1 - mean) * rstd * gam[tid + 256] + bet[tid + 256]);
}

// ---------------------------------------------------------------------------
// v [8192][2048] -> vT [32][512][1024] ([bn][d][s])
// ---------------------------------------------------------------------------
__global__ __launch_bounds__(256) void k_vT(const short* __restrict__ v, short* __restrict__ vT) {
    __shared__ short t[32][34];
    int bn = blockIdx.z, b = bn >> 2, n = bn & 3;
    int s0 = blockIdx.y * 32, d0 = blockIdx.x * 32;
    int lx = threadIdx.x & 31, ly = threadIdx.x >> 5;
#pragma unroll
    for (int i = 0; i < 4; ++i) {
        int s = ly + i * 8;
        t[s][lx] = v[(long)(b * 1024 + s0 + s) * 2048 + n * 512 + d0 + lx];
    }
    __syncthreads();
#pragma unroll
    for (int i = 0; i < 4; ++i) {
        int d = ly + i * 8;
        vT[((long)bn * 512 + d0 + d) * 1024 + s0 + lx] = t[lx][d];
    }
}

// ---------------------------------------------------------------------------
// Persistent LSTM — round-0 protocol VERBATIM. DO NOT TOUCH (rounds 1-4).
// ---------------------------------------------------------------------------
__global__ __launch_bounds__(256) void k_lstm(
    const short* __restrict__ whh, const short* __restrict__ igb,
    short* __restrict__ hA, short* __restrict__ hB,
    short* __restrict__ lstm_pad, int* __restrict__ arr)
{
    const int g = blockIdx.x;            // 0..63, owns units g*16..g*16+15
    const int tid = threadIdx.x;
    const int ln = tid & 63, wv = tid >> 6;
    const int kbase = wv * 256 + ((ln >> 4) << 3);
    const int arow = ln & 15;            // batch rows; 8..15 stay zero

    short8 wf[4][8];
#pragma unroll
    for (int q = 0; q < 4; ++q) {
        long row = (long)q * 1024 + g * 16 + (ln & 15);
#pragma unroll
        for (int kk = 0; kk < 8; ++kk)
            wf[q][kk] = *(const short8*)&whh[row * 1024 + kbase + kk * 32];
    }

    __shared__ float part[4][16][68];
    const int gm = tid >> 4, gu = tid & 15;   // gate threads tid<128: batch, unit
    float c_prev = 0.f;
    float igv[4];
    if (tid < 128) {
#pragma unroll
        for (int q = 0; q < 4; ++q)
            igv[q] = b2f(igb[((long)gm * 1024 + 0) * 4096 + q * 1024 + g * 16 + gu]);
    }

    for (int step = 0; step < 1024; ++step) {
        const short* hp = (step & 1) ? hB : hA;
        short8 af[8];
        if (arow < 8) {
            const unsigned long long* hq =
                (const unsigned long long*)(hp + arow * 1024 + kbase);
#pragma unroll
            for (int kk = 0; kk < 8; ++kk) {
                union { unsigned long long u[2]; short8 s; } cv;
                cv.u[0] = __hip_atomic_load(hq + kk * 8,     __ATOMIC_RELAXED, __HIP_MEMORY_SCOPE_AGENT);
                cv.u[1] = __hip_atomic_load(hq + kk * 8 + 1, __ATOMIC_RELAXED, __HIP_MEMORY_SCOPE_AGENT);
                af[kk] = cv.s;
            }
        } else {
#pragma unroll
            for (int kk = 0; kk < 8; ++kk) af[kk] = (short8){0, 0, 0, 0, 0, 0, 0, 0};
        }

        float4v acc[4];
#pragma unroll
        for (int q = 0; q < 4; ++q) acc[q] = (float4v){0.f, 0.f, 0.f, 0.f};
#pragma unroll
        for (int kk = 0; kk < 8; ++kk)
#pragma unroll
            for (int q = 0; q < 4; ++q)
                acc[q] = __builtin_amdgcn_mfma_f32_16x16x32_bf16(af[kk], wf[q][kk], acc[q], 0, 0, 0);

#pragma unroll
        for (int q = 0; q < 4; ++q)
#pragma unroll
            for (int rr = 0; rr < 4; ++rr)
                part[wv][(ln >> 4) * 4 + rr][q * 16 + (ln & 15)] = acc[q][rr];
        __syncthreads();

        if (tid < 128) {
            float psum[4];
#pragma unroll
            for (int q = 0; q < 4; ++q)
                psum[q] = part[0][gm][q * 16 + gu] + part[1][gm][q * 16 + gu]
                        + part[2][gm][q * 16 + gu] + part[3][gm][q * 16 + gu];
            float g0 = psum[0] + igv[0];
            float g1 = psum[1] + igv[1];
            float g2 = psum[2] + igv[2];
            float g3 = psum[3] + igv[3];
            float iv = 1.f / (1.f + __expf(-g0));
            float fv = 1.f / (1.f + __expf(-g1));
            float gv = 2.f / (1.f + __expf(-2.f * g2)) - 1.f;
            float ov = 1.f / (1.f + __expf(-g3));
            float c = fv * c_prev + iv * gv;
            c_prev = c;
            float h = ov * (2.f / (1.f + __expf(-2.f * c)) - 1.f);
            short hb16 = f2b(h);
            short* hn = (step & 1) ? hA : hB;
            __hip_atomic_store(&hn[gm * 1024 + g * 16 + gu], hb16,
                               __ATOMIC_RELAXED, __HIP_MEMORY_SCOPE_AGENT);
            lstm_pad[((long)gm * 1026 + step + 1) * 1024 + g * 16 + gu] = hb16;
        }

        __syncthreads();   // drain: h stores acked before flag
        if (tid == 0)
            __hip_atomic_store(&arr[g], step + 1, __ATOMIC_RELAXED, __HIP_MEMORY_SCOPE_AGENT);
        if (tid < 128 && step + 1 < 1024) {
#pragma unroll
            for (int q = 0; q < 4; ++q)
                igv[q] = b2f(igb[((long)gm * 1024 + step + 1) * 4096 + q * 1024 + g * 16 + gu]);
        }
        if (wv == 0) {
            const int target = step + 1;
            long att = 0;
            while (true) {
                int f0 = __hip_atomic_load(&arr[ln], __ATOMIC_RELAXED, __HIP_MEMORY_SCOPE_AGENT);
                if (__all(f0 >= target)) break;
                if (++att > 20000000L) break;   // never hang
                __builtin_amdgcn_s_sleep(1);
            }
        }
        __syncthreads();
    }
}

// ---------------------------------------------------------------------------
// conv2 (4x parallel): 256 blocks = 16 bc x 4 t-quarters x 4 channel-chunks.
// a2 pre-initialized with bias in prep; partials atomicAdd'ed.
// Also zeroes d_out (16384 floats) for k_feat's atomic accumulation.
// ---------------------------------------------------------------------------
__global__ __launch_bounds__(256) void k_conv2(const short* __restrict__ a1,
                                               const float* __restrict__ w,
                                               float* __restrict__ a2,
                                               float* __restrict__ dz) {
    __shared__ float wl[384];
    int blk = blockIdx.x;
    int chunk = blk & 3, tq = (blk >> 2) & 3, bc = blk >> 4;
    int b = bc >> 1, c = bc & 1, t0 = tq * 256;
    int tid = threadIdx.x;
    int gid = blk * 256 + tid;
    if (gid < 16384) dz[gid] = 0.f;
    for (int i = tid; i < 384; i += 256) wl[i] = w[c * 1536 + chunk * 384 + i];
    __syncthreads();
    int t = t0 + tid;
    int j0 = chunk * 16;
    float s = 0.f;
    for (int dk = 0; dk < 3; ++dk) {
        int tt = t + dk - 1;
        if (tt < 0 || tt >= 1024) continue;
        const short8* arow = (const short8*)(a1 + (long)(b * 1024 + tt) * 512);
#pragma unroll 4
        for (int j = 0; j < 16; ++j) {
            short8 v = arow[j0 + j];
#pragma unroll
            for (int u = 0; u < 8; ++u)
                s += b2f(v[u]) * wl[(j * 8 + u) * 3 + dk];
        }
    }
    atomicAdd(&a2[(b * 2 + c) * 1024 + t], s);
}

// ---------------------------------------------------------------------------
// feat (4x parallel): 256 blocks = 16 bc x 4 h-quarters x 4 t-chunks.
// Each block redundantly computes the row softmax stats (4 KB read),
// accumulates its 256-t chunk, atomicAdds into d_out (zeroed by conv2).
// ---------------------------------------------------------------------------
__global__ __launch_bounds__(256) void k_feat(const float* __restrict__ a2,
                                              const short* __restrict__ lstm_pad,
                                              float* __restrict__ out) {
    int blk = blockIdx.x;
    int tc = blk & 3, qh = (blk >> 2) & 3, bc = blk >> 4;
    int b = bc >> 1;
    int tid = threadIdx.x;
    int h = qh * 256 + tid;
    __shared__ float aws[256];
    __shared__ float red[4], red2[4];
    float v[4];
    float mx = -3.4e38f;
#pragma unroll
    for (int i = 0; i < 4; ++i) { v[i] = a2[bc * 1024 + tid + (i << 8)]; mx = fmaxf(mx, v[i]); }
#pragma unroll
    for (int d = 32; d > 0; d >>= 1) mx = fmaxf(mx, __shfl_down(mx, d));
    if ((tid & 63) == 0) red[tid >> 6] = mx;
    __syncthreads();
    mx = fmaxf(fmaxf(red[0], red[1]), fmaxf(red[2], red[3]));
    float s = 0.f;
#pragma unroll
    for (int i = 0; i < 4; ++i) { v[i] = __expf(v[i] - mx); s += v[i]; }
#pragma unroll
    for (int d = 32; d > 0; d >>= 1) s += __shfl_down(s, d);
    if ((tid & 63) == 0) red2[tid >> 6] = s;
    __syncthreads();
    s = red2[0] + red2[1] + red2[2] + red2[3];
    float inv = 1.f / s;
    aws[tid] = v[tc] * inv;        // aw[tc*256 + tid]
    __syncthreads();
    float acc = 0.f;
#pragma unroll 16
    for (int j = 0; j < 256; ++j)
        acc += aws[j] * b2f(lstm_pad[((long)(b * 1026 + tc * 256 + j + 1)) * 1024 + h]);
    atomicAdd(&out[bc * 1024 + h], acc);
}

// ---------------------------------------------------------------------------
// Host orchestration
// ---------------------------------------------------------------------------
static void gemm_bt(hipStream_t st, const short* A, const short* B, float* Cf, short* Cb,
                    const float* bias, int M, int N, int K, int lda, int ldb, int ldc,
                    int z, int z0n, long sA0, long sA1, long sB0, long sB1, long sC0, long sC1,
                    int act, int gap, const float* bias2 = nullptr, int nsplit = 0) {
    dim3 grid(N / 128, M / 128, z);
    k_gemm_bt<<<grid, dim3(256), 0, st>>>(A, B, Cf, Cb, bias, M, N, K, lda, ldb, ldc,
                                          z0n, sA0, sA1, sB0, sB1, sC0, sC1, act, gap, bias2, nsplit);
}

static void gemm_bt64(hipStream_t st, const short* A, const short* B, float* Cf, short* Cb,
                      const float* bias, int M, int N, int K, int lda, int ldb, int ldc,
                      int z, int z0n, long sA0, long sA1, long sB0, long sB1, long sC0, long sC1,
                      int act, int gap, const float* bias2 = nullptr, int nsplit = 0) {
    dim3 grid(N / 128, M / 64, z);
    k_gemm_bt64<<<grid, dim3(256), 0, st>>>(A, B, Cf, Cb, bias, M, N, K, lda, ldb, ldc,
                                            z0n, sA0, sA1, sB0, sB1, sC0, sC1, act, gap, bias2, nsplit);
}

extern "C" void kernel_launch(void* const* d_in, const int* in_sizes, int n_in,
                              void* d_out, int out_size, void* d_ws, size_t ws_size,
                              hipStream_t stream) {
    if (ws_size < 199409920u) return;

    const float* x     = (const float*)d_in[0];
    const float* w_in1 = (const float*)d_in[1];
    const float* b_in1 = (const float*)d_in[2];
    const float* w_in2 = (const float*)d_in[3];
    const float* b_in2 = (const float*)d_in[4];
    const float* w_q   = (const float*)d_in[5];
    const float* b_q   = (const float*)d_in[6];
    const float* w_k   = (const float*)d_in[7];
    const float* b_k   = (const float*)d_in[8];
    const float* w_v   = (const float*)d_in[9];
    const float* b_v   = (const float*)d_in[10];
    const float* w_p   = (const float*)d_in[11];
    const float* b_p   = (const float*)d_in[12];
    const float* ln_g  = (const float*)d_in[13];
    const float* ln_b  = (const float*)d_in[14];
    const float* w_ih  = (const float*)d_in[15];
    const float* w_hh  = (const float*)d_in[16];
    const float* b_ih  = (const float*)d_in[17];
    const float* b_hh  = (const float*)d_in[18];
    const float* w_c1  = (const float*)d_in[19];
    const float* b_c1  = (const float*)d_in[20];
    const float* w_c2  = (const float*)d_in[21];
    const float* b_c2  = (const float*)d_in[22];

    char* ws = (char*)d_ws;
    // ---- static region ----
    short* w1b  = (short*)(ws + 0);
    short* w2b  = (short*)(ws + 524288);
    short* wqb  = (short*)(ws + 1048576);   // wqb||wkb contiguous (fused qk B)
    short* wvb  = (short*)(ws + 3145728);
    short* wpb  = (short*)(ws + 5242880);
    short* wihb = (short*)(ws + 7340032);
    short* whhb = (short*)(ws + 11534336);
    short* wc1b = (short*)(ws + 19922944);
    float* bsum = (float*)(ws + 23068672);
    short* hs0  = (short*)(ws + 23085056);     // 32 KB
    short* hs1  = (short*)(ws + 23117824);     // 32 KB
    int*   arr  = (int*)  (ws + 23150592);     // 256 B used
    float* a2   = (float*)(ws + 23150848);
    short* lpad = (short*)(ws + 23216384);
    // ---- dynamic region D0 = 40,026,368 ----
    const size_t D0 = 40026368u;
    short* xbf   = (short*)(ws + D0);
    short* h1bf  = (short*)(ws + D0 + 8388608);
    short* h2bf  = (short*)(ws + D0 + 16777216);
    short* qkC   = (short*)(ws + D0 + 25165824);   // fused q|k [8192][2048], 32 MB
    short* vbf   = (short*)(ws + D0 + 58720256);
    short* vTbf  = (short*)(ws + D0 + 92274688);
    short* scb   = (short*)(ws + D0 + 58720256);   // 32 MB (vbf slot, dead after vT)
    short* obf   = (short*)(ws + D0 + 125829120);
    short* ybf   = (short*)(ws + D0 + 58720256);   // scb dead by then
    short* ylnbf = (short*)(ws + D0 + 67108864);
    short* igb   = (short*)(ws + D0 + 92274688);
    short* a1bf  = (short*)(ws + D0);
    float* cp0   = (float*)(ws + D0 + 8388608);    // conv1 K-split partials (igb dead)
    float* cp1   = (float*)(ws + D0 + 25165824);

    k_cvt_all<<<dim3(4096), dim3(256), 0, stream>>>(
        (const float4v*)x,
        (const float4v*)w_in1, (const float4v*)w_in2, (const float4v*)w_q, (const float4v*)w_k,
        (const float4v*)w_v, (const float4v*)w_p, (const float4v*)w_ih, (const float4v*)w_hh,
        (short4v*)xbf, (short4v*)w1b);
    k_small_prep<<<dim3(128), dim3(256), 0, stream>>>(
        w_c1, wc1b, b_ih, b_hh, bsum, lpad, hs0, hs1, arr, b_c2, a2);

    gemm_bt64(stream, xbf, w1b, nullptr, h1bf, b_in1, 8192, 512, 512, 512, 512, 512,
              1, 1, 0, 0, 0, 0, 0, 0, 1, 0);
    gemm_bt64(stream, h1bf, w2b, nullptr, h2bf, b_in2, 8192, 512, 512, 512, 512, 512,
              1, 1, 0, 0, 0, 0, 0, 0, 0, 0);
    // fused q+k: N=2048, two-segment bias
    gemm_bt(stream, h2bf, wqb, nullptr, qkC, b_q, 8192, 2048, 512, 512, 512, 2048,
            1, 1, 0, 0, 0, 0, 0, 0, 0, 0, b_k, 1024);
    gemm_bt(stream, h2bf, wvb, nullptr, vbf, b_v, 8192, 2048, 512, 512, 512, 2048,
            1, 1, 0, 0, 0, 0, 0, 0, 0, 0);
    k_vT<<<dim3(16, 32, 32), dim3(256), 0, stream>>>(vbf, vTbf);

    // attention: 4 batches per iteration (z = 4 batches x 4 heads = 16)
    for (int bg = 0; bg < 2; ++bg) {
        const short* qb = qkC + (long)bg * 8388608;          // 4 batches x 1024 rows x 2048
        const short* kb = qkC + 1024 + (long)bg * 8388608;   // k half: col offset 1024
        gemm_bt(stream, qb, kb, nullptr, scb, nullptr, 1024, 1024, 256, 2048, 2048, 1024,
                16, 4, 256, 2097152, 256, 2097152, 1048576, 4194304, 0, 0);
        k_softmax_rows_bf16<<<dim3(16384), dim3(256), 0, stream>>>(scb);
        gemm_bt64(stream, scb, vTbf + (long)bg * 8388608, nullptr, obf + (long)bg * 8388608, nullptr,
                  1024, 512, 1024, 1024, 1024, 2048,
                  16, 4, 1048576, 4194304, 524288, 2097152, 512, 2097152, 0, 0);
    }

    gemm_bt64(stream, obf, wpb, nullptr, ybf, b_p, 8192, 512, 2048, 2048, 2048, 512,
              1, 1, 0, 0, 0, 0, 0, 0, 0, 0);
    k_layernorm<<<dim3(8192), dim3(256), 0, stream>>>(ybf, ln_g, ln_b, ylnbf);
    gemm_bt(stream, ylnbf, wihb, nullptr, igb, bsum, 8192, 4096, 512, 512, 512, 4096,
            1, 1, 0, 0, 0, 0, 0, 0, 0, 0);
    k_lstm<<<dim3(64), dim3(256), 0, stream>>>(whhb, igb, hs0, hs1, lpad, arr);
    // conv1 as split-K (z=2, K=1536 each) into f32 partials, then combine
    gemm_bt64(stream, lpad, wc1b, cp0, nullptr, nullptr, 8192, 512, 1536, 1024, 3072, 512,
              2, 2, 1536, 0, 1536, 0, 4194304, 0, 0, 1);
    k_comb1<<<dim3(4096), dim3(256), 0, stream>>>(
        (const float4v*)cp0, (const float4v*)cp1, b_c1, (short4v*)a1bf);
    k_conv2<<<dim3(256), dim3(256), 0, stream>>>(a1bf, w_c2, a2, (float*)d_out);
    k_feat<<<dim3(256), dim3(256), 0, stream>>>(a2, lpad, (float*)d_out);
    (void)in_sizes; (void)n_in; (void)out_size; (void)ws_size;
}

// Round 9
// 3869.598 us; speedup vs baseline: 1.0247x; 1.0092x over previous
//
#include <hip/hip_runtime.h>
#include <stdint.h>

// ---------------------------------------------------------------------------
// Types / helpers
// ---------------------------------------------------------------------------
typedef short short8 __attribute__((ext_vector_type(8)));
typedef short short4v __attribute__((ext_vector_type(4)));
typedef float float4v __attribute__((ext_vector_type(4)));

__device__ __forceinline__ float b2f(short s) {
    return __uint_as_float(((unsigned)(unsigned short)s) << 16);
}
__device__ __forceinline__ short f2b(float f) {
    unsigned u = __float_as_uint(f);
    unsigned r = (u + 0x7fffu + ((u >> 16) & 1u)) >> 16;
    return (short)r;
}

// ---------------------------------------------------------------------------
// One prep kernel: fp32->bf16 for x + 8 weight buffers, wc1 transpose+cvt,
// bias sums/concat, zero lpad pad-rows / h bufs / flags, a2 bias-init.
// ---------------------------------------------------------------------------
__global__ void k_prep_all(const float4v* __restrict__ xs,
                           const float4v* __restrict__ s0, const float4v* __restrict__ s1,
                           const float4v* __restrict__ s2, const float4v* __restrict__ s3,
                           const float4v* __restrict__ s4, const float4v* __restrict__ s5,
                           const float4v* __restrict__ s6, const float4v* __restrict__ s7,
                           short4v* __restrict__ xq, short4v* __restrict__ wq,
                           const float* __restrict__ wc1, short* __restrict__ wc1b,
                           const float* __restrict__ bih, const float* __restrict__ bhh,
                           float* __restrict__ bsum,
                           const float* __restrict__ bq, const float* __restrict__ bk,
                           const float* __restrict__ bv, float* __restrict__ bqkv,
                           short* __restrict__ lpad,
                           short* __restrict__ hs0, short* __restrict__ hs1,
                           int* __restrict__ arr, const float* __restrict__ bc2,
                           float* __restrict__ a2) {
    int t0 = blockIdx.x * blockDim.x + threadIdx.x;
    int stride = gridDim.x * blockDim.x;
    for (int i = t0; i < 3538944; i += stride) {
        float4v v;
        short4v* dst;
        int di;
        if (i < 1048576) { v = xs[i]; dst = xq; di = i; }
        else {
            int j = i - 1048576;
            dst = wq; di = j;
            if      (j <   65536) v = s0[j];
            else if (j <  131072) v = s1[j -   65536];
            else if (j <  262144) v = s2[j -  131072];
            else if (j <  393216) v = s3[j -  262144];
            else if (j <  655360) v = s4[j -  393216];
            else if (j <  917504) v = s5[j -  655360];
            else if (j < 1441792) v = s6[j -  917504];
            else                  v = s7[j - 1441792];
        }
        short4v o;
        o[0] = f2b(v[0]); o[1] = f2b(v[1]); o[2] = f2b(v[2]); o[3] = f2b(v[3]);
        dst[di] = o;
    }
    for (int i = t0; i < 512 * 3072; i += stride) {
        int c = i / 3072, rr = i % 3072, dk = rr / 1024, h = rr % 1024;
        wc1b[i] = f2b(wc1[(c * 1024 + h) * 3 + dk]);
    }
    for (int i = t0; i < 4096; i += stride) bsum[i] = bih[i] + bhh[i];
    for (int i = t0; i < 4096; i += stride) {
        float v;
        if (i < 1024) v = bq[i];
        else if (i < 2048) v = bk[i - 1024];
        else v = bv[i - 2048];
        bqkv[i] = v;
    }
    for (int i = t0; i < 16 * 1024; i += stride) {
        int b = i >> 11, r = (i >> 10) & 1, h = i & 1023;
        lpad[((long)(b * 1026 + r * 1025)) * 1024 + h] = 0;
    }
    for (int i = t0; i < 16384; i += stride) { hs0[i] = 0; hs1[i] = 0; }
    for (int i = t0; i < 64; i += stride) arr[i] = 0;
    for (int i = t0; i < 16384; i += stride) a2[i] = bc2[(i >> 10) & 1];
}

// ---------------------------------------------------------------------------
// Generic batched GEMM (BM=128).  Cvt/vtn0: block-uniform epilogue routing —
// tiles with tn0 >= vtn0 write directly in vT layout ([b*4+n][d][s], packed
// short4 per thread since r=0..3 -> consecutive s). Used by the fused QKV
// projection to eliminate the separate v buffer + transpose kernel.
// ---------------------------------------------------------------------------
__global__ __launch_bounds__(256) void k_gemm_bt(
    const short* __restrict__ A, const short* __restrict__ B,
    float* __restrict__ Cf, short* __restrict__ Cb,
    const float* __restrict__ bias,
    int M, int N, int K, int lda, int ldb, int ldc,
    int z0n, long sA0, long sA1, long sB0, long sB1, long sC0, long sC1,
    int act, int gap, short* __restrict__ Cvt, int vtn0)
{
    __shared__ __align__(16) short lds[2 * 128 * 32];
    const int z = blockIdx.z;
    const int z0 = z % z0n, z1 = z / z0n;
    A += z1 * sA1 + z0 * sA0;
    B += z1 * sB1 + z0 * sB0;
    const long coff = z1 * sC1 + z0 * sC0;
    const int tn0 = blockIdx.x * 128, tm0 = blockIdx.y * 128;
    const int tid = threadIdx.x, ln = tid & 63, wv = tid >> 6;
    const int wr = wv >> 1, wc = wv & 1;

    const short* gbase[4];
    {
        const int gcol = (ln & 3) ^ ((ln >> 3) & 3);
#pragma unroll
        for (int j = 0; j < 4; ++j) {
            int c = wv * 4 + j;
            if (c < 8) {
                long grow = (long)(tm0 + c * 16 + (ln >> 2));
                if (gap) grow += 2 * (grow >> 10);
                gbase[j] = A + grow * (long)lda + gcol * 8;
            } else {
                gbase[j] = B + (long)(tn0 + (c - 8) * 16 + (ln >> 2)) * ldb + gcol * 8;
            }
        }
    }

    float4v acc[4][4];
#pragma unroll
    for (int i = 0; i < 4; ++i)
#pragma unroll
        for (int j = 0; j < 4; ++j) acc[i][j] = (float4v){0.f, 0.f, 0.f, 0.f};

    const int nk = K >> 5;
    for (int kt = 0; kt < nk; ++kt) {
        __syncthreads();
#pragma unroll
        for (int j = 0; j < 4; ++j) {
            int c = wv * 4 + j;
            __builtin_amdgcn_global_load_lds(
                (const __attribute__((address_space(1))) void*)(gbase[j] + kt * 32),
                (__attribute__((address_space(3))) void*)((short8*)lds + c * 64),
                16, 0, 0);
        }
        __syncthreads();

        short8 af[4], bf_[4];
        const int q = ln >> 4;
#pragma unroll
        for (int i = 0; i < 4; ++i) {
            int r = wr * 64 + i * 16 + (ln & 15);
            af[i] = ((short8*)lds)[r * 4 + (q ^ ((r >> 1) & 3))];
        }
#pragma unroll
        for (int j = 0; j < 4; ++j) {
            int r = wc * 64 + j * 16 + (ln & 15);
            bf_[j] = ((short8*)lds)[512 + r * 4 + (q ^ ((r >> 1) & 3))];
        }
#pragma unroll
        for (int i = 0; i < 4; ++i)
#pragma unroll
            for (int j = 0; j < 4; ++j)
                acc[i][j] = __builtin_amdgcn_mfma_f32_16x16x32_bf16(af[i], bf_[j], acc[i][j], 0, 0, 0);
    }

    if (Cvt && tn0 >= vtn0) {
        // vT-layout epilogue: C[m][nv] -> vT[(b*4 + nv/512)*512 + nv%512][s]
#pragma unroll
        for (int j = 0; j < 4; ++j) {
            int nglob = tn0 + wc * 64 + j * 16 + (ln & 15);
            float bv = bias ? bias[nglob] : 0.f;
            int nv = nglob - vtn0;
            int nn = nv >> 9, d = nv & 511;
#pragma unroll
            for (int i = 0; i < 4; ++i) {
                int m0 = tm0 + wr * 64 + i * 16 + (ln >> 4) * 4;
                int b = m0 >> 10, s = m0 & 1023;
                short4v pk;
#pragma unroll
                for (int r = 0; r < 4; ++r) pk[r] = f2b(acc[i][j][r] + bv);
                *(short4v*)&Cvt[((long)((b * 4 + nn) * 512 + d)) * 1024 + s] = pk;
            }
        }
        return;
    }

#pragma unroll
    for (int j = 0; j < 4; ++j) {
        int nglob = tn0 + wc * 64 + j * 16 + (ln & 15);
        float bv = bias ? bias[nglob] : 0.f;
#pragma unroll
        for (int i = 0; i < 4; ++i) {
#pragma unroll
            for (int r = 0; r < 4; ++r) {
                int mglob = tm0 + wr * 64 + i * 16 + (ln >> 4) * 4 + r;
                float v = acc[i][j][r] + bv;
                if (act == 1) v = (v >= 0.f) ? v : 0.25f * v;
                else if (act == 2) v = fmaxf(v, 0.f);
                long ci = coff + (long)mglob * ldc + nglob;
                if (Cf) Cf[ci] = v;
                if (Cb) Cb[ci] = f2b(v);
            }
        }
    }
}

// ---------------------------------------------------------------------------
// BM=64 variant (64x128 tile).
// ---------------------------------------------------------------------------
__global__ __launch_bounds__(256) void k_gemm_bt64(
    const short* __restrict__ A, const short* __restrict__ B,
    float* __restrict__ Cf, short* __restrict__ Cb,
    const float* __restrict__ bias,
    int M, int N, int K, int lda, int ldb, int ldc,
    int z0n, long sA0, long sA1, long sB0, long sB1, long sC0, long sC1,
    int act, int gap)
{
    __shared__ __align__(16) short lds[(64 + 128) * 32];
    const int z = blockIdx.z;
    const int z0 = z % z0n, z1 = z / z0n;
    A += z1 * sA1 + z0 * sA0;
    B += z1 * sB1 + z0 * sB0;
    const long coff = z1 * sC1 + z0 * sC0;
    const int tn0 = blockIdx.x * 128, tm0 = blockIdx.y * 64;
    const int tid = threadIdx.x, ln = tid & 63, wv = tid >> 6;
    const int wr = wv >> 1, wc = wv & 1;

    const short* gbase[3];
    {
        const int gcol = (ln & 3) ^ ((ln >> 3) & 3);
#pragma unroll
        for (int j = 0; j < 3; ++j) {
            int c = wv * 3 + j;
            if (c < 4) {
                long grow = (long)(tm0 + c * 16 + (ln >> 2));
                if (gap) grow += 2 * (grow >> 10);
                gbase[j] = A + grow * (long)lda + gcol * 8;
            } else {
                gbase[j] = B + (long)(tn0 + (c - 4) * 16 + (ln >> 2)) * ldb + gcol * 8;
            }
        }
    }

    float4v acc[2][4];
#pragma unroll
    for (int i = 0; i < 2; ++i)
#pragma unroll
        for (int j = 0; j < 4; ++j) acc[i][j] = (float4v){0.f, 0.f, 0.f, 0.f};

    const int nk = K >> 5;
    for (int kt = 0; kt < nk; ++kt) {
        __syncthreads();
#pragma unroll
        for (int j = 0; j < 3; ++j) {
            int c = wv * 3 + j;
            __builtin_amdgcn_global_load_lds(
                (const __attribute__((address_space(1))) void*)(gbase[j] + kt * 32),
                (__attribute__((address_space(3))) void*)((short8*)lds + c * 64),
                16, 0, 0);
        }
        __syncthreads();

        short8 af[2], bf_[4];
        const int q = ln >> 4;
#pragma unroll
        for (int i = 0; i < 2; ++i) {
            int r = wr * 32 + i * 16 + (ln & 15);
            af[i] = ((short8*)lds)[r * 4 + (q ^ ((r >> 1) & 3))];
        }
#pragma unroll
        for (int j = 0; j < 4; ++j) {
            int r = wc * 64 + j * 16 + (ln & 15);
            bf_[j] = ((short8*)lds)[256 + r * 4 + (q ^ ((r >> 1) & 3))];
        }
#pragma unroll
        for (int i = 0; i < 2; ++i)
#pragma unroll
            for (int j = 0; j < 4; ++j)
                acc[i][j] = __builtin_amdgcn_mfma_f32_16x16x32_bf16(af[i], bf_[j], acc[i][j], 0, 0, 0);
    }

#pragma unroll
    for (int j = 0; j < 4; ++j) {
        int nglob = tn0 + wc * 64 + j * 16 + (ln & 15);
        float bv = bias ? bias[nglob] : 0.f;
#pragma unroll
        for (int i = 0; i < 2; ++i) {
#pragma unroll
            for (int r = 0; r < 4; ++r) {
                int mglob = tm0 + wr * 32 + i * 16 + (ln >> 4) * 4 + r;
                float v = acc[i][j][r] + bv;
                if (act == 1) v = (v >= 0.f) ? v : 0.25f * v;
                else if (act == 2) v = fmaxf(v, 0.f);
                long ci = coff + (long)mglob * ldc + nglob;
                if (Cf) Cf[ci] = v;
                if (Cb) Cb[ci] = f2b(v);
            }
        }
    }
}

// ---------------------------------------------------------------------------
// conv1 combine: a1 = bf16(relu(p0 + p1 + b_c1[n]))
// ---------------------------------------------------------------------------
__global__ __launch_bounds__(256) void k_comb1(const float4v* __restrict__ p0,
                                               const float4v* __restrict__ p1,
                                               const float* __restrict__ bias,
                                               short4v* __restrict__ o) {
    int i = blockIdx.x * blockDim.x + threadIdx.x;
    int stride = gridDim.x * blockDim.x;
    for (; i < 1048576; i += stride) {
        float4v a = p0[i], b = p1[i];
        short4v r;
#pragma unroll
        for (int u = 0; u < 4; ++u) {
            float v = a[u] + b[u] + bias[(i * 4 + u) & 511];
            r[u] = f2b(fmaxf(v, 0.f));
        }
        o[i] = r;
    }
}

// ---------------------------------------------------------------------------
// Row softmax over 1024, bf16 in-place
// ---------------------------------------------------------------------------
__global__ __launch_bounds__(256) void k_softmax_rows_bf16(short* __restrict__ p) {
    long row = blockIdx.x;
    short* r = p + (row << 10);
    int tid = threadIdx.x;
    float v[4];
    float mx = -3.4e38f;
#pragma unroll
    for (int i = 0; i < 4; ++i) { v[i] = b2f(r[tid + (i << 8)]); mx = fmaxf(mx, v[i]); }
#pragma unroll
    for (int d = 32; d > 0; d >>= 1) mx = fmaxf(mx, __shfl_down(mx, d));
    __shared__ float red[4], red2[4];
    if ((tid & 63) == 0) red[tid >> 6] = mx;
    __syncthreads();
    mx = fmaxf(fmaxf(red[0], red[1]), fmaxf(red[2], red[3]));
    float s = 0.f;
#pragma unroll
    for (int i = 0; i < 4; ++i) { v[i] = __expf(v[i] - mx); s += v[i]; }
#pragma unroll
    for (int d = 32; d > 0; d >>= 1) s += __shfl_down(s, d);
    if ((tid & 63) == 0) red2[tid >> 6] = s;
    __syncthreads();
    s = red2[0] + red2[1] + red2[2] + red2[3];
    float inv = 1.f / s;
#pragma unroll
    for (int i = 0; i < 4; ++i) r[tid + (i << 8)] = f2b(v[i] * inv);
}

// ---------------------------------------------------------------------------
// LayerNorm over E=512 (bf16 in -> bf16 out), rows = 8192
// ---------------------------------------------------------------------------
__global__ __launch_bounds__(256) void k_layernorm(const short* __restrict__ y,
                                                   const float* __restrict__ gam,
                                                   const float* __restrict__ bet,
                                                   short* __restrict__ o) {
    const long row = blockIdx.x;
    const short* r = y + (row << 9);
    const int tid = threadIdx.x;
    float v0 = b2f(r[tid]), v1 = b2f(r[tid + 256]);
    float s = v0 + v1, ss = v0 * v0 + v1 * v1;
#pragma unroll
    for (int d = 32; d > 0; d >>= 1) { s += __shfl_down(s, d); ss += __shfl_down(ss, d); }
    __shared__ float rs_[4], rss[4];
    if ((tid & 63) == 0) { rs_[tid >> 6] = s; rss[tid >> 6] = ss; }
    __syncthreads();
    s = rs_[0] + rs_[1] + rs_[2] + rs_[3];
    ss = rss[0] + rss[1] + rss[2] + rss[3];
    float mean = s * (1.f / 512.f);
    float var = ss * (1.f / 512.f) - mean * mean;
    float rstd = rsqrtf(var + 1e-5f);
    short* out = o + (row << 9);
    out[tid]       = f2b((v0 - mean) * rstd * gam[tid]       + bet[tid]);
    out[tid + 256] = f2b((v1 - mean) * rstd * gam[tid + 256] + bet[tid + 256]);
}

// ---------------------------------------------------------------------------
// Persistent LSTM — round-0 protocol VERBATIM. DO NOT TOUCH (rounds 1-4).
// ---------------------------------------------------------------------------
__global__ __launch_bounds__(256) void k_lstm(
    const short* __restrict__ whh, const short* __restrict__ igb,
    short* __restrict__ hA, short* __restrict__ hB,
    short* __restrict__ lstm_pad, int* __restrict__ arr)
{
    const int g = blockIdx.x;            // 0..63, owns units g*16..g*16+15
    const int tid = threadIdx.x;
    const int ln = tid & 63, wv = tid >> 6;
    const int kbase = wv * 256 + ((ln >> 4) << 3);
    const int arow = ln & 15;            // batch rows; 8..15 stay zero

    short8 wf[4][8];
#pragma unroll
    for (int q = 0; q < 4; ++q) {
        long row = (long)q * 1024 + g * 16 + (ln & 15);
#pragma unroll
        for (int kk = 0; kk < 8; ++kk)
            wf[q][kk] = *(const short8*)&whh[row * 1024 + kbase + kk * 32];
    }

    __shared__ float part[4][16][68];
    const int gm = tid >> 4, gu = tid & 15;   // gate threads tid<128: batch, unit
    float c_prev = 0.f;
    float igv[4];
    if (tid < 128) {
#pragma unroll
        for (int q = 0; q < 4; ++q)
            igv[q] = b2f(igb[((long)gm * 1024 + 0) * 4096 + q * 1024 + g * 16 + gu]);
    }

    for (int step = 0; step < 1024; ++step) {
        const short* hp = (step & 1) ? hB : hA;
        short8 af[8];
        if (arow < 8) {
            const unsigned long long* hq =
                (const unsigned long long*)(hp + arow * 1024 + kbase);
#pragma unroll
            for (int kk = 0; kk < 8; ++kk) {
                union { unsigned long long u[2]; short8 s; } cv;
                cv.u[0] = __hip_atomic_load(hq + kk * 8,     __ATOMIC_RELAXED, __HIP_MEMORY_SCOPE_AGENT);
                cv.u[1] = __hip_atomic_load(hq + kk * 8 + 1, __ATOMIC_RELAXED, __HIP_MEMORY_SCOPE_AGENT);
                af[kk] = cv.s;
            }
        } else {
#pragma unroll
            for (int kk = 0; kk < 8; ++kk) af[kk] = (short8){0, 0, 0, 0, 0, 0, 0, 0};
        }

        float4v acc[4];
#pragma unroll
        for (int q = 0; q < 4; ++q) acc[q] = (float4v){0.f, 0.f, 0.f, 0.f};
#pragma unroll
        for (int kk = 0; kk < 8; ++kk)
#pragma unroll
            for (int q = 0; q < 4; ++q)
                acc[q] = __builtin_amdgcn_mfma_f32_16x16x32_bf16(af[kk], wf[q][kk], acc[q], 0, 0, 0);

#pragma unroll
        for (int q = 0; q < 4; ++q)
#pragma unroll
            for (int rr = 0; rr < 4; ++rr)
                part[wv][(ln >> 4) * 4 + rr][q * 16 + (ln & 15)] = acc[q][rr];
        __syncthreads();

        if (tid < 128) {
            float psum[4];
#pragma unroll
            for (int q = 0; q < 4; ++q)
                psum[q] = part[0][gm][q * 16 + gu] + part[1][gm][q * 16 + gu]
                        + part[2][gm][q * 16 + gu] + part[3][gm][q * 16 + gu];
            float g0 = psum[0] + igv[0];
            float g1 = psum[1] + igv[1];
            float g2 = psum[2] + igv[2];
            float g3 = psum[3] + igv[3];
            float iv = 1.f / (1.f + __expf(-g0));
            float fv = 1.f / (1.f + __expf(-g1));
            float gv = 2.f / (1.f + __expf(-2.f * g2)) - 1.f;
            float ov = 1.f / (1.f + __expf(-g3));
            float c = fv * c_prev + iv * gv;
            c_prev = c;
            float h = ov * (2.f / (1.f + __expf(-2.f * c)) - 1.f);
            short hb16 = f2b(h);
            short* hn = (step & 1) ? hA : hB;
            __hip_atomic_store(&hn[gm * 1024 + g * 16 + gu], hb16,
                               __ATOMIC_RELAXED, __HIP_MEMORY_SCOPE_AGENT);
            lstm_pad[((long)gm * 1026 + step + 1) * 1024 + g * 16 + gu] = hb16;
        }

        __syncthreads();   // drain: h stores acked before flag
        if (tid == 0)
            __hip_atomic_store(&arr[g], step + 1, __ATOMIC_RELAXED, __HIP_MEMORY_SCOPE_AGENT);
        if (tid < 128 && step + 1 < 1024) {
#pragma unroll
            for (int q = 0; q < 4; ++q)
                igv[q] = b2f(igb[((long)gm * 1024 + step + 1) * 4096 + q * 1024 + g * 16 + gu]);
        }
        if (wv == 0) {
            const int target = step + 1;
            long att = 0;
            while (true) {
                int f0 = __hip_atomic_load(&arr[ln], __ATOMIC_RELAXED, __HIP_MEMORY_SCOPE_AGENT);
                if (__all(f0 >= target)) break;
                if (++att > 20000000L) break;   // never hang
                __builtin_amdgcn_s_sleep(1);
            }
        }
        __syncthreads();
    }
}

// ---------------------------------------------------------------------------
// conv2 (4x parallel): 256 blocks = 16 bc x 4 t-quarters x 4 channel-chunks.
// a2 pre-initialized with bias in prep; partials atomicAdd'ed.
// Also zeroes d_out (16384 floats) for k_feat's atomic accumulation.
// ---------------------------------------------------------------------------
__global__ __launch_bounds__(256) void k_conv2(const short* __restrict__ a1,
                                               const float* __restrict__ w,
                                               float* __restrict__ a2,
                                               float* __restrict__ dz) {
    __shared__ float wl[384];
    int blk = blockIdx.x;
    int chunk = blk & 3, tq = (blk >> 2) & 3, bc = blk >> 4;
    int b = bc >> 1, c = bc & 1, t0 = tq * 256;
    int tid = threadIdx.x;
    int gid = blk * 256 + tid;
    if (gid < 16384) dz[gid] = 0.f;
    for (int i = tid; i < 384; i += 256) wl[i] = w[c * 1536 + chunk * 384 + i];
    __syncthreads();
    int t = t0 + tid;
    int j0 = chunk * 16;
    float s = 0.f;
    for (int dk = 0; dk < 3; ++dk) {
        int tt = t + dk - 1;
        if (tt < 0 || tt >= 1024) continue;
        const short8* arow = (const short8*)(a1 + (long)(b * 1024 + tt) * 512);
#pragma unroll 4
        for (int j = 0; j < 16; ++j) {
            short8 v = arow[j0 + j];
#pragma unroll
            for (int u = 0; u < 8; ++u)
                s += b2f(v[u]) * wl[(j * 8 + u) * 3 + dk];
        }
    }
    atomicAdd(&a2[(b * 2 + c) * 1024 + t], s);
}

// ---------------------------------------------------------------------------
// feat (4x parallel): 256 blocks = 16 bc x 4 h-quarters x 4 t-chunks.
// ---------------------------------------------------------------------------
__global__ __launch_bounds__(256) void k_feat(const float* __restrict__ a2,
                                              const short* __restrict__ lstm_pad,
                                              float* __restrict__ out) {
    int blk = blockIdx.x;
    int tc = blk & 3, qh = (blk >> 2) & 3, bc = blk >> 4;
    int b = bc >> 1;
    int tid = threadIdx.x;
    int h = qh * 256 + tid;
    __shared__ float aws[256];
    __shared__ float red[4], red2[4];
    float v[4];
    float mx = -3.4e38f;
#pragma unroll
    for (int i = 0; i < 4; ++i) { v[i] = a2[bc * 1024 + tid + (i << 8)]; mx = fmaxf(mx, v[i]); }
#pragma unroll
    for (int d = 32; d > 0; d >>= 1) mx = fmaxf(mx, __shfl_down(mx, d));
    if ((tid & 63) == 0) red[tid >> 6] = mx;
    __syncthreads();
    mx = fmaxf(fmaxf(red[0], red[1]), fmaxf(red[2], red[3]));
    float s = 0.f;
#pragma unroll
    for (int i = 0; i < 4; ++i) { v[i] = __expf(v[i] - mx); s += v[i]; }
#pragma unroll
    for (int d = 32; d > 0; d >>= 1) s += __shfl_down(s, d);
    if ((tid & 63) == 0) red2[tid >> 6] = s;
    __syncthreads();
    s = red2[0] + red2[1] + red2[2] + red2[3];
    float inv = 1.f / s;
    aws[tid] = v[tc] * inv;        // aw[tc*256 + tid]
    __syncthreads();
    float acc = 0.f;
#pragma unroll 16
    for (int j = 0; j < 256; ++j)
        acc += aws[j] * b2f(lstm_pad[((long)(b * 1026 + tc * 256 + j + 1)) * 1024 + h]);
    atomicAdd(&out[bc * 1024 + h], acc);
}

// ---------------------------------------------------------------------------
// Host orchestration
// ---------------------------------------------------------------------------
static void gemm_bt(hipStream_t st, const short* A, const short* B, float* Cf, short* Cb,
                    const float* bias, int M, int N, int K, int lda, int ldb, int ldc,
                    int z, int z0n, long sA0, long sA1, long sB0, long sB1, long sC0, long sC1,
                    int act, int gap, short* Cvt = nullptr, int vtn0 = 0) {
    dim3 grid(N / 128, M / 128, z);
    k_gemm_bt<<<grid, dim3(256), 0, st>>>(A, B, Cf, Cb, bias, M, N, K, lda, ldb, ldc,
                                          z0n, sA0, sA1, sB0, sB1, sC0, sC1, act, gap, Cvt, vtn0);
}

static void gemm_bt64(hipStream_t st, const short* A, const short* B, float* Cf, short* Cb,
                      const float* bias, int M, int N, int K, int lda, int ldb, int ldc,
                      int z, int z0n, long sA0, long sA1, long sB0, long sB1, long sC0, long sC1,
                      int act, int gap) {
    dim3 grid(N / 128, M / 64, z);
    k_gemm_bt64<<<grid, dim3(256), 0, st>>>(A, B, Cf, Cb, bias, M, N, K, lda, ldb, ldc,
                                            z0n, sA0, sA1, sB0, sB1, sC0, sC1, act, gap);
}

extern "C" void kernel_launch(void* const* d_in, const int* in_sizes, int n_in,
                              void* d_out, int out_size, void* d_ws, size_t ws_size,
                              hipStream_t stream) {
    if (ws_size < 199409920u) return;

    const float* x     = (const float*)d_in[0];
    const float* w_in1 = (const float*)d_in[1];
    const float* b_in1 = (const float*)d_in[2];
    const float* w_in2 = (const float*)d_in[3];
    const float* b_in2 = (const float*)d_in[4];
    const float* w_q   = (const float*)d_in[5];
    const float* b_q   = (const float*)d_in[6];
    const float* w_k   = (const float*)d_in[7];
    const float* b_k   = (const float*)d_in[8];
    const float* w_v   = (const float*)d_in[9];
    const float* b_v   = (const float*)d_in[10];
    const float* w_p   = (const float*)d_in[11];
    const float* b_p   = (const float*)d_in[12];
    const float* ln_g  = (const float*)d_in[13];
    const float* ln_b  = (const float*)d_in[14];
    const float* w_ih  = (const float*)d_in[15];
    const float* w_hh  = (const float*)d_in[16];
    const float* b_ih  = (const float*)d_in[17];
    const float* b_hh  = (const float*)d_in[18];
    const float* w_c1  = (const float*)d_in[19];
    const float* b_c1  = (const float*)d_in[20];
    const float* w_c2  = (const float*)d_in[21];
    const float* b_c2  = (const float*)d_in[22];

    char* ws = (char*)d_ws;
    // ---- static region ----
    short* w1b  = (short*)(ws + 0);
    short* w2b  = (short*)(ws + 524288);
    short* wqb  = (short*)(ws + 1048576);   // wq||wk||wv contiguous (fused QKV B)
    short* wpb  = (short*)(ws + 5242880);
    short* wihb = (short*)(ws + 7340032);
    short* whhb = (short*)(ws + 11534336);
    short* wc1b = (short*)(ws + 19922944);
    float* bsum = (float*)(ws + 23068672);
    short* hs0  = (short*)(ws + 23085056);     // 32 KB
    short* hs1  = (short*)(ws + 23117824);     // 32 KB
    int*   arr  = (int*)  (ws + 23150592);     // 256 B used
    float* a2   = (float*)(ws + 23150848);
    short* lpad = (short*)(ws + 23216384);
    // ---- dynamic region D0 = 40,026,368 ----
    const size_t D0 = 40026368u;
    short* xbf   = (short*)(ws + D0);
    short* h1bf  = (short*)(ws + D0 + 8388608);
    short* h2bf  = (short*)(ws + D0 + 16777216);
    short* qkC   = (short*)(ws + D0 + 25165824);   // fused q|k [8192][2048], 32 MB
    float* bqkv  = (float*)(ws + D0 + 58720256);   // 16 KB, dead before scb
    short* vTbf  = (short*)(ws + D0 + 92274688);
    short* scb   = (short*)(ws + D0 + 58720256);   // 32 MB (free slot, after bqkv use)
    short* obf   = (short*)(ws + D0 + 125829120);
    short* ybf   = (short*)(ws + D0 + 58720256);   // scb dead by then
    short* ylnbf = (short*)(ws + D0 + 67108864);
    short* igb   = (short*)(ws + D0 + 92274688);
    short* a1bf  = (short*)(ws + D0);
    float* cp0   = (float*)(ws + D0 + 8388608);    // conv1 K-split partials (igb dead)
    float* cp1   = (float*)(ws + D0 + 25165824);

    k_prep_all<<<dim3(4096), dim3(256), 0, stream>>>(
        (const float4v*)x,
        (const float4v*)w_in1, (const float4v*)w_in2, (const float4v*)w_q, (const float4v*)w_k,
        (const float4v*)w_v, (const float4v*)w_p, (const float4v*)w_ih, (const float4v*)w_hh,
        (short4v*)xbf, (short4v*)w1b,
        w_c1, wc1b, b_ih, b_hh, bsum, b_q, b_k, b_v, bqkv,
        lpad, hs0, hs1, arr, b_c2, a2);

    gemm_bt64(stream, xbf, w1b, nullptr, h1bf, b_in1, 8192, 512, 512, 512, 512, 512,
              1, 1, 0, 0, 0, 0, 0, 0, 1, 0);
    gemm_bt64(stream, h1bf, w2b, nullptr, h2bf, b_in2, 8192, 512, 512, 512, 512, 512,
              1, 1, 0, 0, 0, 0, 0, 0, 0, 0);
    // fused QKV: N=4096; n<2048 -> qkC [8192][2048]; n>=2048 -> vT layout direct
    gemm_bt(stream, h2bf, wqb, nullptr, qkC, bqkv, 8192, 4096, 512, 512, 512, 2048,
            1, 1, 0, 0, 0, 0, 0, 0, 0, 0, vTbf, 2048);

    // attention: 4 batches per iteration (z = 4 batches x 4 heads = 16)
    for (int bg = 0; bg < 2; ++bg) {
        const short* qb = qkC + (long)bg * 8388608;          // 4 batches x 1024 rows x 2048
        const short* kb = qkC + 1024 + (long)bg * 8388608;   // k half: col offset 1024
        gemm_bt(stream, qb, kb, nullptr, scb, nullptr, 1024, 1024, 256, 2048, 2048, 1024,
                16, 4, 256, 2097152, 256, 2097152, 1048576, 4194304, 0, 0);
        k_softmax_rows_bf16<<<dim3(16384), dim3(256), 0, stream>>>(scb);
        gemm_bt64(stream, scb, vTbf + (long)bg * 8388608, nullptr, obf + (long)bg * 8388608, nullptr,
                  1024, 512, 1024, 1024, 1024, 2048,
                  16, 4, 1048576, 4194304, 524288, 2097152, 512, 2097152, 0, 0);
    }

    gemm_bt64(stream, obf, wpb, nullptr, ybf, b_p, 8192, 512, 2048, 2048, 2048, 512,
              1, 1, 0, 0, 0, 0, 0, 0, 0, 0);
    k_layernorm<<<dim3(8192), dim3(256), 0, stream>>>(ybf, ln_g, ln_b, ylnbf);
    gemm_bt(stream, ylnbf, wihb, nullptr, igb, bsum, 8192, 4096, 512, 512, 512, 4096,
            1, 1, 0, 0, 0, 0, 0, 0, 0, 0);
    k_lstm<<<dim3(64), dim3(256), 0, stream>>>(whhb, igb, hs0, hs1, lpad, arr);
    // conv1 as split-K (z=2, K=1536 each) into f32 partials, then combine
    gemm_bt64(stream, lpad, wc1b, cp0, nullptr, nullptr, 8192, 512, 1536, 1024, 3072, 512,
              2, 2, 1536, 0, 1536, 0, 4194304, 0, 0, 1);
    k_comb1<<<dim3(4096), dim3(256), 0, stream>>>(
        (const float4v*)cp0, (const float4v*)cp1, b_c1, (short4v*)a1bf);
    k_conv2<<<dim3(256), dim3(256), 0, stream>>>(a1bf, w_c2, a2, (float*)d_out);
    k_feat<<<dim3(256), dim3(256), 0, stream>>>(a2, lpad, (float*)d_out);
    (void)in_sizes; (void)n_in; (void)out_size; (void)ws_size;
}